// Round 1
// baseline (372.191 us; speedup 1.0000x reference)
//
#include <hip/hip_runtime.h>
#include <cstdint>
#include <cstddef>

// Problem constants
#define BB   2
#define SS   1024
#define HID  2048
#define HH   32
#define KVHH 8
#define DD   64
#define NQKV 3072   // fused QKV projection width: 2048 q + 512 k + 512 v
#define QKW  2560   // qk_bf row width: 2048 q + 512 k

typedef __attribute__((ext_vector_type(8))) short bf16x8;
typedef __attribute__((ext_vector_type(4))) float f32x4;
typedef __attribute__((ext_vector_type(4))) unsigned int u32x4;

__device__ __forceinline__ unsigned short f2bf(float f) {
    unsigned int u = __float_as_uint(f);
    unsigned int r = (u + 0x7fffu + ((u >> 16) & 1u)) >> 16;
    return (unsigned short)r;
}

// async global->LDS 16B (wave-uniform LDS base + lane*16 layout required)
__device__ __forceinline__ void g2l16(const unsigned short* g, unsigned short* l) {
    __builtin_amdgcn_global_load_lds(
        (__attribute__((address_space(1))) void*)(unsigned short*)g,
        (__attribute__((address_space(3))) void*)l,
        16, 0, 0);
}

// ---------------------------------------------------------------------------
// prep (vectorized): z=0..3 weight transpose+convert (64x64 tiles, float4
// reads, ushort4 writes); z=4 hidden fp32->bf16 straight convert.
// ---------------------------------------------------------------------------
__global__ __launch_bounds__(256) void prep(
    const float* __restrict__ hidden,
    const float* __restrict__ Wq, const float* __restrict__ Wk,
    const float* __restrict__ Wv, const float* __restrict__ Wo,
    unsigned short* __restrict__ hidden_bf,
    unsigned short* __restrict__ WqkvT,
    unsigned short* __restrict__ WoT)
{
    const int z   = blockIdx.z;
    const int tid = threadIdx.x;

    if (z == 4) {   // hidden convert, 2048x2048, 64x64 tile
        int r0 = blockIdx.y * 64, c0 = blockIdx.x * 64;
        #pragma unroll
        for (int p = 0; p < 4; ++p) {
            int f = tid + p * 256;            // 0..1023
            int row = r0 + (f >> 4), c4 = c0 + (f & 15) * 4;
            float4 v = *(const float4*)&hidden[(size_t)row * 2048 + c4];
            ushort4 o;
            o.x = f2bf(v.x); o.y = f2bf(v.y); o.z = f2bf(v.z); o.w = f2bf(v.w);
            *(ushort4*)&hidden_bf[(size_t)row * 2048 + c4] = o;
        }
        return;
    }

    const float* W;
    unsigned short* Wt;
    int N;
    if (z == 0)      { W = Wq; Wt = WqkvT;                        N = 2048; }
    else if (z == 1) { W = Wk; Wt = WqkvT + (size_t)2048 * 2048;  N = 512;  }
    else if (z == 2) { W = Wv; Wt = WqkvT + (size_t)2560 * 2048;  N = 512;  }
    else             { W = Wo; Wt = WoT;                          N = 2048; }
    if (blockIdx.x * 64 >= N) return;

    // 64x64 transpose tile via LDS, stride 68 (2-way bank alias only)
    __shared__ float t[64][68];
    const int n0 = blockIdx.x * 64, k0 = blockIdx.y * 64;
    #pragma unroll
    for (int p = 0; p < 4; ++p) {
        int f = tid + p * 256;
        int row = f >> 4, c4 = (f & 15) * 4;     // row=k_local, c4=n_local
        float4 v = *(const float4*)&W[(size_t)(k0 + row) * N + n0 + c4];
        t[row][c4 + 0] = v.x; t[row][c4 + 1] = v.y;
        t[row][c4 + 2] = v.z; t[row][c4 + 3] = v.w;
    }
    __syncthreads();
    #pragma unroll
    for (int p = 0; p < 4; ++p) {
        int f = tid + p * 256;
        int nrow = f >> 4, kc4 = (f & 15) * 4;   // output row=n, col=k
        ushort4 o;
        o.x = f2bf(t[kc4 + 0][nrow]);
        o.y = f2bf(t[kc4 + 1][nrow]);
        o.z = f2bf(t[kc4 + 2][nrow]);
        o.w = f2bf(t[kc4 + 3][nrow]);
        *(ushort4*)&Wt[(size_t)(n0 + nrow) * 2048 + k0 + kc4] = o;
    }
}

// ---------------------------------------------------------------------------
// Fused QKV GEMM + rope/V-transpose epilogue. Tile 128(M) x 64(N), BK=32,
// async global_load_lds staging. Grid (48, 16): bx<32 -> q head bx;
// bx 32..39 -> k head bx-32; bx 40..47 -> v head bx-40.
// ---------------------------------------------------------------------------
__global__ __launch_bounds__(256) void gemm_qkv_fused(
    const unsigned short* __restrict__ A,     // hidden_bf [2048][2048]
    const unsigned short* __restrict__ Bt,    // WqkvT [3072][2048]
    unsigned short* __restrict__ qk_bf,       // [2048][2560]
    unsigned short* __restrict__ v_t)         // [1024][1024]
{
    __shared__ short As[128][32];   // 8 KB
    __shared__ short Bs[64][32];    // 4 KB
    __shared__ float Ct[128][65];   // 32.5 KB

    const int tid  = threadIdx.x;
    const int lane = tid & 63;
    const int wave = tid >> 6;
    const int wm = (wave >> 1) * 64, wn = (wave & 1) * 32;
    const int m0 = blockIdx.y * 128, n0 = blockIdx.x * 64;
    const int K = 2048;

    f32x4 acc[4][2] = {};

    const int mrow = lane & 15;
    const int kq   = (lane >> 4) * 8;
    const int quad = lane >> 4;
    const int l15  = lane & 15;

    for (int k0 = 0; k0 < K; k0 += 32) {
        #pragma unroll
        for (int p = 0; p < 2; ++p) {   // A: 512 x 16B chunks
            int ci = tid + p * 256;
            int row = ci >> 2;
            int q = (ci & 3) * 8;
            g2l16(&A[(size_t)(m0 + row) * K + k0 + q],
                  (unsigned short*)&As[0][0] + ci * 8);
        }
        {   // B: 256 x 16B chunks
            int ci = tid;
            int row = ci >> 2;
            int q = (ci & 3) * 8;
            g2l16(&Bt[(size_t)(n0 + row) * K + k0 + q],
                  (unsigned short*)&Bs[0][0] + ci * 8);
        }
        __syncthreads();

        bf16x8 af[4], bfr[2];
        #pragma unroll
        for (int i = 0; i < 4; ++i)
            af[i] = *(const bf16x8*)&As[wm + i * 16 + mrow][kq];
        #pragma unroll
        for (int j = 0; j < 2; ++j)
            bfr[j] = *(const bf16x8*)&Bs[wn + j * 16 + mrow][kq];

        #pragma unroll
        for (int i = 0; i < 4; ++i)
            #pragma unroll
            for (int j = 0; j < 2; ++j)
                acc[i][j] = __builtin_amdgcn_mfma_f32_16x16x32_bf16(
                    af[i], bfr[j], acc[i][j], 0, 0, 0);
        __syncthreads();
    }

    // ---- epilogue: fragments -> LDS fp32 tile ----
    #pragma unroll
    for (int i = 0; i < 4; ++i)
        #pragma unroll
        for (int j = 0; j < 2; ++j)
            #pragma unroll
            for (int rg = 0; rg < 4; ++rg)
                Ct[wm + i * 16 + quad * 4 + rg][wn + j * 16 + l15] = acc[i][j][rg];
    __syncthreads();

    const int bx = blockIdx.x;
    const int b  = m0 >> 10;           // batch (tile never straddles)
    const int s0 = m0 & 1023;

    if (bx < 40) {
        // rope q/k: qk_bf col base = bx*64 (q: 0..2047; k: 2048 + (bx-32)*64)
        const int hc = bx * 64;
        const float scale = (bx < 32) ? 0.125f : 1.0f;
        #pragma unroll
        for (int p = 0; p < 4; ++p) {
            int idx = tid + p * 256;          // 128 rows x 8 t-groups
            int row = idx >> 3, t0 = (idx & 7) * 4;
            int s = s0 + row;
            ushort4 o1, o2;
            #pragma unroll
            for (int k = 0; k < 4; ++k) {
                int t = t0 + k;
                float x1 = Ct[row][t];
                float x2 = Ct[row][t + 32];
                float inv = __expf(-(float)t * 0.28782313662425572f);
                float ang = (float)s * inv;
                float c  = __cosf(ang);
                float sn = __sinf(ang);
                ((unsigned short*)&o1)[k] = f2bf((x1 * c - x2 * sn) * scale);
                ((unsigned short*)&o2)[k] = f2bf((x2 * c + x1 * sn) * scale);
            }
            unsigned short* dst = qk_bf + (size_t)(m0 + row) * QKW + hc;
            *(ushort4*)&dst[t0]      = o1;
            *(ushort4*)&dst[t0 + 32] = o2;
        }
    } else {
        // v transpose: v_t[(b*512 + (bx-40)*64 + c)][s0 + srow]
        const int vb = b * 512 + (bx - 40) * 64;
        #pragma unroll
        for (int p = 0; p < 8; ++p) {
            int idx = tid + p * 256;          // 64 c x 32 s-groups
            int c = idx >> 5, srow = (idx & 31) * 4;
            ushort4 o;
            #pragma unroll
            for (int k = 0; k < 4; ++k)
                ((unsigned short*)&o)[k] = f2bf(Ct[srow + k][c]);
            *(ushort4*)&v_t[(size_t)(vb + c) * 1024 + s0 + srow] = o;
        }
    }
}

// ---------------------------------------------------------------------------
// bf16 MFMA GEMM, B-transposed (Wo projection). Tile 128x64, BK=32.
// ---------------------------------------------------------------------------
__global__ __launch_bounds__(256) void gemm_bf16_bt(
    const unsigned short* __restrict__ A,
    const unsigned short* __restrict__ Bt,
    float* __restrict__ C, int M, int N, int K)
{
    __shared__ short As[128][32];   // 8 KB
    __shared__ short Bs[64][32];    // 4 KB

    const int tid  = threadIdx.x;
    const int lane = tid & 63;
    const int wave = tid >> 6;
    const int wm = (wave >> 1) * 64, wn = (wave & 1) * 32;
    const int m0 = blockIdx.y * 128, n0 = blockIdx.x * 64;

    f32x4 acc[4][2] = {};

    const int mrow = lane & 15;
    const int kq   = (lane >> 4) * 8;

    for (int k0 = 0; k0 < K; k0 += 32) {
        #pragma unroll
        for (int p = 0; p < 2; ++p) {   // A: 512 x 16B chunks
            int ci = tid + p * 256;
            int row = ci >> 2;
            int q = (ci & 3) * 8;
            g2l16(&A[(size_t)(m0 + row) * K + k0 + q],
                  (unsigned short*)&As[0][0] + ci * 8);
        }
        {   // B: 256 x 16B chunks
            int ci = tid;
            int row = ci >> 2;
            int q = (ci & 3) * 8;
            g2l16(&Bt[(size_t)(n0 + row) * K + k0 + q],
                  (unsigned short*)&Bs[0][0] + ci * 8);
        }
        __syncthreads();

        bf16x8 af[4], bfr[2];
        #pragma unroll
        for (int i = 0; i < 4; ++i)
            af[i] = *(const bf16x8*)&As[wm + i * 16 + mrow][kq];
        #pragma unroll
        for (int j = 0; j < 2; ++j)
            bfr[j] = *(const bf16x8*)&Bs[wn + j * 16 + mrow][kq];

        #pragma unroll
        for (int i = 0; i < 4; ++i)
            #pragma unroll
            for (int j = 0; j < 2; ++j)
                acc[i][j] = __builtin_amdgcn_mfma_f32_16x16x32_bf16(
                    af[i], bfr[j], acc[i][j], 0, 0, 0);
        __syncthreads();
    }

    #pragma unroll
    for (int i = 0; i < 4; ++i) {
        int grow = m0 + wm + i * 16 + (lane >> 4) * 4;
        #pragma unroll
        for (int j = 0; j < 2; ++j) {
            int gcol = n0 + wn + j * 16 + (lane & 15);
            #pragma unroll
            for (int rg = 0; rg < 4; ++rg)
                C[(size_t)(grow + rg) * N + gcol] = acc[i][j][rg];
        }
    }
}

// ---------------------------------------------------------------------------
// MFMA flash attention, two-pass, barrier-free j-loop.
// Swapped-operand QK^T: S^T = mfma(K, Q) so each lane's P row is lane-local
// (q = lane&15). Q hoisted to registers; K/V fragments read directly from
// global (L2-resident; each 64-lane load = 16 x 64B lines). P handed to PV
// in-register via v_cvt_pk_bf16_f32 + shfl_xor(16) quad-pair exchange, with
// V columns read in the matching permuted kpos order (bijection per 64-tile;
// legal since PV sums over k). Only LDS left: bias_diag slice (4 KB).
// ---------------------------------------------------------------------------
__global__ __launch_bounds__(256, 3) void attn_mfma(
    const unsigned short* __restrict__ qk_bf,   // [2048][2560]
    const unsigned short* __restrict__ v_t,     // [1024][1024]
    const float* __restrict__ bias_diag,
    const float* __restrict__ soff,
    unsigned short* __restrict__ AO)            // [2048][2048] bf16
{
    const int qt = 15 - (int)blockIdx.x;        // big tiles dispatched first
    const int h  = blockIdx.y;
    const int b  = blockIdx.z;
    const int kh = h >> 2;
    const int tid  = threadIdx.x;
    const int lane = tid & 63;
    const int wave = tid >> 6;
    const int quad = lane >> 4;
    const int l15  = lane & 15;
    const int q0   = qt * 64;

    __shared__ float bd_s[1024];
    for (int i = tid; i < 1024; i += 256) bd_s[i] = bias_diag[h * 1024 + i];
    __syncthreads();

    const unsigned short* Qg = qk_bf + (size_t)(b * SS + q0 + wave * 16) * QKW + h * 64;
    const unsigned short* Kg = qk_bf + (size_t)(b * SS) * QKW + 2048 + kh * 64;
    const unsigned short* Vg = v_t + (size_t)(b * 512 + kh * 64) * SS;

    // lane-constant fragment offsets (elements)
    const int koff = l15 * QKW + quad * 8;                      // K frags
    const int voff = l15 * SS + ((quad & 1) << 4) + ((quad >> 1) << 3); // V frags
    const int qrow = q0 + wave * 16 + l15;      // this lane's q (S^T column)

    // Q fragments (B operand), hoisted for the whole kernel: rows l15
    bf16x8 qf0 = *(const bf16x8*)(Qg + (size_t)l15 * QKW + quad * 8);
    bf16x8 qf1 = *(const bf16x8*)(Qg + (size_t)l15 * QKW + 32 + quad * 8);

    float lp = 0.f;

    // ---------------- pass 1: l ----------------
    for (int j = 0; j < qt; ++j) {              // full tiles: mask-free
        const unsigned short* Kj = Kg + (size_t)j * 64 * QKW;
        f32x4 acc[4] = {};
        #pragma unroll
        for (int nb = 0; nb < 4; ++nb) {
            bf16x8 a0 = *(const bf16x8*)(Kj + koff + nb * 16 * QKW);
            bf16x8 a1 = *(const bf16x8*)(Kj + koff + nb * 16 * QKW + 32);
            acc[nb] = __builtin_amdgcn_mfma_f32_16x16x32_bf16(a0, qf0, acc[nb], 0, 0, 0);
            acc[nb] = __builtin_amdgcn_mfma_f32_16x16x32_bf16(a1, qf1, acc[nb], 0, 0, 0);
        }
        #pragma unroll
        for (int nb = 0; nb < 4; ++nb) {
            int rel0 = qrow - (j * 64 + nb * 16 + quad * 4);
            #pragma unroll
            for (int r = 0; r < 4; ++r)
                lp += __expf(acc[nb][r] + bd_s[rel0 - r]);
        }
    }
    {   // diagonal tile j = qt (masked; sub-tiles nb > wave are fully dead)
        const unsigned short* Kj = Kg + (size_t)qt * 64 * QKW;
        f32x4 acc[4] = {};
        #pragma unroll
        for (int nb = 0; nb < 4; ++nb) if (nb <= wave) {
            bf16x8 a0 = *(const bf16x8*)(Kj + koff + nb * 16 * QKW);
            bf16x8 a1 = *(const bf16x8*)(Kj + koff + nb * 16 * QKW + 32);
            acc[nb] = __builtin_amdgcn_mfma_f32_16x16x32_bf16(a0, qf0, acc[nb], 0, 0, 0);
            acc[nb] = __builtin_amdgcn_mfma_f32_16x16x32_bf16(a1, qf1, acc[nb], 0, 0, 0);
        }
        #pragma unroll
        for (int nb = 0; nb < 4; ++nb) if (nb <= wave) {
            #pragma unroll
            for (int r = 0; r < 4; ++r) {
                int rel = qrow - (q0 + nb * 16 + quad * 4 + r);
                if (rel >= 0) lp += __expf(acc[nb][r] + bd_s[rel]);
            }
        }
    }

    lp += __shfl_xor(lp, 16, 64);
    lp += __shfl_xor(lp, 32, 64);
    const float invl = 1.f / lp;
    const float cl   = fabsf(soff[h] + 1.f) / (float)(qrow + 1) * lp;

    // ---------------- pass 2: output ----------------
    f32x4 oacc[4] = {};
    for (int j = 0; j <= qt; ++j) {
        const bool diag = (j == qt);
        const unsigned short* Kj = Kg + (size_t)j * 64 * QKW;
        const unsigned short* Vj = Vg + j * 64;

        f32x4 acc[4] = {};
        #pragma unroll
        for (int nb = 0; nb < 4; ++nb) if (!diag || nb <= wave) {
            bf16x8 a0 = *(const bf16x8*)(Kj + koff + nb * 16 * QKW);
            bf16x8 a1 = *(const bf16x8*)(Kj + koff + nb * 16 * QKW + 32);
            acc[nb] = __builtin_amdgcn_mfma_f32_16x16x32_bf16(a0, qf0, acc[nb], 0, 0, 0);
            acc[nb] = __builtin_amdgcn_mfma_f32_16x16x32_bf16(a1, qf1, acc[nb], 0, 0, 0);
        }

        // w = relu(exp(s + bias) - cl) for this lane's q=l15, kpos quad*4+r
        unsigned int pk[4][2];
        #pragma unroll
        for (int nb = 0; nb < 4; ++nb) {
            float w[4];
            #pragma unroll
            for (int r = 0; r < 4; ++r) {
                int rel = qrow - (j * 64 + nb * 16 + quad * 4 + r);
                float e = 0.f;
                if (rel >= 0)
                    e = fmaxf(__expf(acc[nb][r] + bd_s[rel]) - cl, 0.f);
                w[r] = e;
            }
            asm("v_cvt_pk_bf16_f32 %0, %1, %2" : "=v"(pk[nb][0]) : "v"(w[0]), "v"(w[1]));
            asm("v_cvt_pk_bf16_f32 %0, %1, %2" : "=v"(pk[nb][1]) : "v"(w[2]), "v"(w[3]));
        }
        unsigned int ppk[4][2];
        #pragma unroll
        for (int nb = 0; nb < 4; ++nb) {
            ppk[nb][0] = __shfl_xor(pk[nb][0], 16, 64);
            ppk[nb][1] = __shfl_xor(pk[nb][1], 16, 64);
        }

        // PV with permuted k-slots: slot quad*8+e <-> kpos 16*(2s+(quad&1)) +
        // 8*(quad>>1) + e; V read at the same permuted column base (voff).
        const bool oddq = quad & 1;
        #pragma unroll
        for (int s = 0; s < 2; ++s) {
            if (diag && s == 1 && wave < 2) continue;   // dead kpos block
            unsigned int w0 = oddq ? ppk[2 * s + 1][0] : pk[2 * s][0];
            unsigned int w1 = oddq ? ppk[2 * s + 1][1] : pk[2 * s][1];
            unsigned int w2 = oddq ? pk[2 * s + 1][0]  : ppk[2 * s][0];
            unsigned int w3 = oddq ? pk[2 * s + 1][1]  : ppk[2 * s][1];
            u32x4 t; t[0] = w0; t[1] = w1; t[2] = w2; t[3] = w3;
            bf16x8 pf = __builtin_bit_cast(bf16x8, t);
            #pragma unroll
            for (int nd = 0; nd < 4; ++nd) {
                bf16x8 vf = *(const bf16x8*)(Vj + voff + nd * 16 * SS + s * 32);
                oacc[nd] = __builtin_amdgcn_mfma_f32_16x16x32_bf16(pf, vf, oacc[nd], 0, 0, 0);
            }
        }
    }

    // invl for this lane's OUTPUT rows (q-sub = quad*4+r): fetch from the
    // lane whose l15 equals that row (all quads hold the reduced value).
    float invl_r[4];
    #pragma unroll
    for (int r = 0; r < 4; ++r)
        invl_r[r] = __shfl(invl, quad * 4 + r, 64);

    unsigned short* aop = AO + (size_t)(b * SS + q0 + wave * 16 + quad * 4) * 2048
                             + h * 64 + l15;
    #pragma unroll
    for (int nd = 0; nd < 4; ++nd)
        #pragma unroll
        for (int r = 0; r < 4; ++r)
            aop[(size_t)r * 2048 + nd * 16] = f2bf(oacc[nd][r] * invl_r[r]);
}

// ---------------------------------------------------------------------------
extern "C" void kernel_launch(void* const* d_in, const int* in_sizes, int n_in,
                              void* d_out, int out_size, void* d_ws, size_t ws_size,
                              hipStream_t stream)
{
    const float* hidden    = (const float*)d_in[0];
    const float* Wq        = (const float*)d_in[2];
    const float* Wk        = (const float*)d_in[3];
    const float* Wv        = (const float*)d_in[4];
    const float* Wo        = (const float*)d_in[5];
    const float* bias_diag = (const float*)d_in[6];
    const float* soff      = (const float*)d_in[7];
    float* out = (float*)d_out;

    // Workspace aliasing:
    //  A [0,20.97M): hidden_bf(8.39) + WqkvT(12.58) -- inputs of QKV gemm.
    //                AO_bf at [12.58M..) only AFTER WqkvT is dead (attention
    //                writes AO_bf after the QKV gemm consumed WqkvT).
    //  B [20.97M,29.36M): WoT
    //  C [29.36M,41.94M): qk_bf(10.49M) + v_t(2.10M)
    char* wsb = (char*)d_ws;
    unsigned short* hidden_bf = (unsigned short*)wsb;
    unsigned short* WqkvT     = (unsigned short*)(wsb + (size_t)8388608);
    unsigned short* AO_bf     = (unsigned short*)(wsb + (size_t)12582912);
    unsigned short* WoT       = (unsigned short*)(wsb + (size_t)20971520);
    unsigned short* qk_bf     = (unsigned short*)(wsb + (size_t)29360128);
    unsigned short* v_t       = (unsigned short*)(wsb + (size_t)29360128 + (size_t)2048 * 2560 * 2);

    // 1. weight transposes + hidden convert (one launch, vectorized)
    prep<<<dim3(32, 32, 5), dim3(256), 0, stream>>>(
        hidden, Wq, Wk, Wv, Wo, hidden_bf, WqkvT, WoT);

    // 2. fused QKV projection + rope/V-transpose epilogue
    gemm_qkv_fused<<<dim3(48, 16), dim3(256), 0, stream>>>(
        hidden_bf, WqkvT, qk_bf, v_t);

    // 3. two-pass barrier-free MFMA attention -> AO_bf
    attn_mfma<<<dim3(16, HH, BB), dim3(256), 0, stream>>>(
        qk_bf, v_t, bias_diag, soff, AO_bf);

    // 4. output projection
    gemm_bf16_bt<<<dim3(2048 / 64, 2048 / 128), dim3(256), 0, stream>>>(
        AO_bf, WoT, out, 2048, 2048, 2048);
}

// Round 2
// 264.177 us; speedup vs baseline: 1.4089x; 1.4089x over previous
//
#include <hip/hip_runtime.h>
#include <cstdint>
#include <cstddef>

// Problem constants
#define BB   2
#define SS   1024
#define HID  2048
#define HH   32
#define KVHH 8
#define DD   64
#define NQKV 3072   // fused QKV projection width: 2048 q + 512 k + 512 v
#define QKW  2560   // qk_bf row width: 2048 q + 512 k

typedef __attribute__((ext_vector_type(8))) short bf16x8;
typedef __attribute__((ext_vector_type(4))) float f32x4;
typedef __attribute__((ext_vector_type(4))) unsigned int u32x4;

__device__ __forceinline__ unsigned short f2bf(float f) {
    unsigned int u = __float_as_uint(f);
    unsigned int r = (u + 0x7fffu + ((u >> 16) & 1u)) >> 16;
    return (unsigned short)r;
}

// async global->LDS 16B (wave-uniform LDS base + lane*16 layout required)
__device__ __forceinline__ void g2l16(const unsigned short* g, unsigned short* l) {
    __builtin_amdgcn_global_load_lds(
        (__attribute__((address_space(1))) void*)(unsigned short*)g,
        (__attribute__((address_space(3))) void*)l,
        16, 0, 0);
}

// ---------------------------------------------------------------------------
// prep (vectorized): z=0..3 weight transpose+convert (64x64 tiles, float4
// reads, ushort4 writes); z=4 hidden fp32->bf16 straight convert.
// ---------------------------------------------------------------------------
__global__ __launch_bounds__(256) void prep(
    const float* __restrict__ hidden,
    const float* __restrict__ Wq, const float* __restrict__ Wk,
    const float* __restrict__ Wv, const float* __restrict__ Wo,
    unsigned short* __restrict__ hidden_bf,
    unsigned short* __restrict__ WqkvT,
    unsigned short* __restrict__ WoT)
{
    const int z   = blockIdx.z;
    const int tid = threadIdx.x;

    if (z == 4) {   // hidden convert, 2048x2048, 64x64 tile
        int r0 = blockIdx.y * 64, c0 = blockIdx.x * 64;
        #pragma unroll
        for (int p = 0; p < 4; ++p) {
            int f = tid + p * 256;            // 0..1023
            int row = r0 + (f >> 4), c4 = c0 + (f & 15) * 4;
            float4 v = *(const float4*)&hidden[(size_t)row * 2048 + c4];
            ushort4 o;
            o.x = f2bf(v.x); o.y = f2bf(v.y); o.z = f2bf(v.z); o.w = f2bf(v.w);
            *(ushort4*)&hidden_bf[(size_t)row * 2048 + c4] = o;
        }
        return;
    }

    const float* W;
    unsigned short* Wt;
    int N;
    if (z == 0)      { W = Wq; Wt = WqkvT;                        N = 2048; }
    else if (z == 1) { W = Wk; Wt = WqkvT + (size_t)2048 * 2048;  N = 512;  }
    else if (z == 2) { W = Wv; Wt = WqkvT + (size_t)2560 * 2048;  N = 512;  }
    else             { W = Wo; Wt = WoT;                          N = 2048; }
    if (blockIdx.x * 64 >= N) return;

    // 64x64 transpose tile via LDS, stride 68 (2-way bank alias only)
    __shared__ float t[64][68];
    const int n0 = blockIdx.x * 64, k0 = blockIdx.y * 64;
    #pragma unroll
    for (int p = 0; p < 4; ++p) {
        int f = tid + p * 256;
        int row = f >> 4, c4 = (f & 15) * 4;     // row=k_local, c4=n_local
        float4 v = *(const float4*)&W[(size_t)(k0 + row) * N + n0 + c4];
        t[row][c4 + 0] = v.x; t[row][c4 + 1] = v.y;
        t[row][c4 + 2] = v.z; t[row][c4 + 3] = v.w;
    }
    __syncthreads();
    #pragma unroll
    for (int p = 0; p < 4; ++p) {
        int f = tid + p * 256;
        int nrow = f >> 4, kc4 = (f & 15) * 4;   // output row=n, col=k
        ushort4 o;
        o.x = f2bf(t[kc4 + 0][nrow]);
        o.y = f2bf(t[kc4 + 1][nrow]);
        o.z = f2bf(t[kc4 + 2][nrow]);
        o.w = f2bf(t[kc4 + 3][nrow]);
        *(ushort4*)&Wt[(size_t)(n0 + nrow) * 2048 + k0 + kc4] = o;
    }
}

// ---------------------------------------------------------------------------
// Fused QKV GEMM + rope/V-transpose epilogue. Tile 128(M) x 64(N), BK=32,
// async global_load_lds staging. Grid (48, 16): bx<32 -> q head bx;
// bx 32..39 -> k head bx-32; bx 40..47 -> v head bx-40.
// ---------------------------------------------------------------------------
__global__ __launch_bounds__(256) void gemm_qkv_fused(
    const unsigned short* __restrict__ A,     // hidden_bf [2048][2048]
    const unsigned short* __restrict__ Bt,    // WqkvT [3072][2048]
    unsigned short* __restrict__ qk_bf,       // [2048][2560]
    unsigned short* __restrict__ v_t)         // [1024][1024]
{
    __shared__ short As[128][32];   // 8 KB
    __shared__ short Bs[64][32];    // 4 KB
    __shared__ float Ct[128][65];   // 32.5 KB

    const int tid  = threadIdx.x;
    const int lane = tid & 63;
    const int wave = tid >> 6;
    const int wm = (wave >> 1) * 64, wn = (wave & 1) * 32;
    const int m0 = blockIdx.y * 128, n0 = blockIdx.x * 64;
    const int K = 2048;

    f32x4 acc[4][2] = {};

    const int mrow = lane & 15;
    const int kq   = (lane >> 4) * 8;
    const int quad = lane >> 4;
    const int l15  = lane & 15;

    for (int k0 = 0; k0 < K; k0 += 32) {
        #pragma unroll
        for (int p = 0; p < 2; ++p) {   // A: 512 x 16B chunks
            int ci = tid + p * 256;
            int row = ci >> 2;
            int q = (ci & 3) * 8;
            g2l16(&A[(size_t)(m0 + row) * K + k0 + q],
                  (unsigned short*)&As[0][0] + ci * 8);
        }
        {   // B: 256 x 16B chunks
            int ci = tid;
            int row = ci >> 2;
            int q = (ci & 3) * 8;
            g2l16(&Bt[(size_t)(n0 + row) * K + k0 + q],
                  (unsigned short*)&Bs[0][0] + ci * 8);
        }
        __syncthreads();

        bf16x8 af[4], bfr[2];
        #pragma unroll
        for (int i = 0; i < 4; ++i)
            af[i] = *(const bf16x8*)&As[wm + i * 16 + mrow][kq];
        #pragma unroll
        for (int j = 0; j < 2; ++j)
            bfr[j] = *(const bf16x8*)&Bs[wn + j * 16 + mrow][kq];

        #pragma unroll
        for (int i = 0; i < 4; ++i)
            #pragma unroll
            for (int j = 0; j < 2; ++j)
                acc[i][j] = __builtin_amdgcn_mfma_f32_16x16x32_bf16(
                    af[i], bfr[j], acc[i][j], 0, 0, 0);
        __syncthreads();
    }

    // ---- epilogue: fragments -> LDS fp32 tile ----
    #pragma unroll
    for (int i = 0; i < 4; ++i)
        #pragma unroll
        for (int j = 0; j < 2; ++j)
            #pragma unroll
            for (int rg = 0; rg < 4; ++rg)
                Ct[wm + i * 16 + quad * 4 + rg][wn + j * 16 + l15] = acc[i][j][rg];
    __syncthreads();

    const int bx = blockIdx.x;
    const int b  = m0 >> 10;           // batch (tile never straddles)
    const int s0 = m0 & 1023;

    if (bx < 40) {
        // rope q/k: qk_bf col base = bx*64 (q: 0..2047; k: 2048 + (bx-32)*64)
        const int hc = bx * 64;
        const float scale = (bx < 32) ? 0.125f : 1.0f;
        #pragma unroll
        for (int p = 0; p < 4; ++p) {
            int idx = tid + p * 256;          // 128 rows x 8 t-groups
            int row = idx >> 3, t0 = (idx & 7) * 4;
            int s = s0 + row;
            ushort4 o1, o2;
            #pragma unroll
            for (int k = 0; k < 4; ++k) {
                int t = t0 + k;
                float x1 = Ct[row][t];
                float x2 = Ct[row][t + 32];
                float inv = __expf(-(float)t * 0.28782313662425572f);
                float ang = (float)s * inv;
                float c  = __cosf(ang);
                float sn = __sinf(ang);
                ((unsigned short*)&o1)[k] = f2bf((x1 * c - x2 * sn) * scale);
                ((unsigned short*)&o2)[k] = f2bf((x2 * c + x1 * sn) * scale);
            }
            unsigned short* dst = qk_bf + (size_t)(m0 + row) * QKW + hc;
            *(ushort4*)&dst[t0]      = o1;
            *(ushort4*)&dst[t0 + 32] = o2;
        }
    } else {
        // v transpose: v_t[(b*512 + (bx-40)*64 + c)][s0 + srow]
        const int vb = b * 512 + (bx - 40) * 64;
        #pragma unroll
        for (int p = 0; p < 8; ++p) {
            int idx = tid + p * 256;          // 64 c x 32 s-groups
            int c = idx >> 5, srow = (idx & 31) * 4;
            ushort4 o;
            #pragma unroll
            for (int k = 0; k < 4; ++k)
                ((unsigned short*)&o)[k] = f2bf(Ct[srow + k][c]);
            *(ushort4*)&v_t[(size_t)(vb + c) * 1024 + s0 + srow] = o;
        }
    }
}

// ---------------------------------------------------------------------------
// bf16 MFMA GEMM, B-transposed (Wo projection). Tile 128x64, BK=32.
// ---------------------------------------------------------------------------
__global__ __launch_bounds__(256) void gemm_bf16_bt(
    const unsigned short* __restrict__ A,
    const unsigned short* __restrict__ Bt,
    float* __restrict__ C, int M, int N, int K)
{
    __shared__ short As[128][32];   // 8 KB
    __shared__ short Bs[64][32];    // 4 KB

    const int tid  = threadIdx.x;
    const int lane = tid & 63;
    const int wave = tid >> 6;
    const int wm = (wave >> 1) * 64, wn = (wave & 1) * 32;
    const int m0 = blockIdx.y * 128, n0 = blockIdx.x * 64;

    f32x4 acc[4][2] = {};

    const int mrow = lane & 15;
    const int kq   = (lane >> 4) * 8;

    for (int k0 = 0; k0 < K; k0 += 32) {
        #pragma unroll
        for (int p = 0; p < 2; ++p) {   // A: 512 x 16B chunks
            int ci = tid + p * 256;
            int row = ci >> 2;
            int q = (ci & 3) * 8;
            g2l16(&A[(size_t)(m0 + row) * K + k0 + q],
                  (unsigned short*)&As[0][0] + ci * 8);
        }
        {   // B: 256 x 16B chunks
            int ci = tid;
            int row = ci >> 2;
            int q = (ci & 3) * 8;
            g2l16(&Bt[(size_t)(n0 + row) * K + k0 + q],
                  (unsigned short*)&Bs[0][0] + ci * 8);
        }
        __syncthreads();

        bf16x8 af[4], bfr[2];
        #pragma unroll
        for (int i = 0; i < 4; ++i)
            af[i] = *(const bf16x8*)&As[wm + i * 16 + mrow][kq];
        #pragma unroll
        for (int j = 0; j < 2; ++j)
            bfr[j] = *(const bf16x8*)&Bs[wn + j * 16 + mrow][kq];

        #pragma unroll
        for (int i = 0; i < 4; ++i)
            #pragma unroll
            for (int j = 0; j < 2; ++j)
                acc[i][j] = __builtin_amdgcn_mfma_f32_16x16x32_bf16(
                    af[i], bfr[j], acc[i][j], 0, 0, 0);
        __syncthreads();
    }

    #pragma unroll
    for (int i = 0; i < 4; ++i) {
        int grow = m0 + wm + i * 16 + (lane >> 4) * 4;
        #pragma unroll
        for (int j = 0; j < 2; ++j) {
            int gcol = n0 + wn + j * 16 + (lane & 15);
            #pragma unroll
            for (int rg = 0; rg < 4; ++rg)
                C[(size_t)(grow + rg) * N + gcol] = acc[i][j][rg];
        }
    }
}

// ---------------------------------------------------------------------------
// MFMA flash attention, two-pass. Swapped-operand QK^T (verified r1):
// S^T = mfma(K, Q), P lane-local, in-register P->PV via cvt_pk + shfl_xor.
// K/V tiles staged into LDS via double-buffered global_load_lds (2-phase:
// issue next tile's stage at loop top, one barrier per tile). Since
// global_load_lds writes linearly, the T2 bank-conflict swizzle is applied
// on the GLOBAL source chunk index (c' = c ^ (row&7), involution) and the
// fragment reads use the same XOR -> conflict-free ds_read_b128.
// LDS: Ks 16KB + Vs 16KB + bd_s 4KB = 36KB -> 4 blocks/CU.
// ---------------------------------------------------------------------------
__global__ __launch_bounds__(256, 4) void attn_mfma(
    const unsigned short* __restrict__ qk_bf,   // [2048][2560]
    const unsigned short* __restrict__ v_t,     // [1024][1024]
    const float* __restrict__ bias_diag,
    const float* __restrict__ soff,
    unsigned short* __restrict__ AO)            // [2048][2048] bf16
{
    const int qt = 15 - (int)blockIdx.x;        // big tiles dispatched first
    const int h  = blockIdx.y;
    const int b  = blockIdx.z;
    const int kh = h >> 2;
    const int tid  = threadIdx.x;
    const int lane = tid & 63;
    const int wave = tid >> 6;
    const int quad = lane >> 4;
    const int l15  = lane & 15;
    const int q0   = qt * 64;

    __shared__ short Ks[2][4096];   // [64 rows][64 cols] bf16, chunk-swizzled
    __shared__ short Vs[2][4096];   // [64 d][64 k] bf16, chunk-swizzled
    __shared__ float bd_s[1024];

    for (int i = tid; i < 1024; i += 256) bd_s[i] = bias_diag[h * 1024 + i];

    const unsigned short* Qg = qk_bf + (size_t)(b * SS + q0 + wave * 16) * QKW + h * 64;
    const unsigned short* Kg = qk_bf + (size_t)(b * SS) * QKW + 2048 + kh * 64;
    const unsigned short* Vg = v_t + (size_t)(b * 512 + kh * 64) * SS;

    const int qrow = q0 + wave * 16 + l15;      // this lane's q (S^T column)

    // Q fragments (B operand), hoisted for the whole kernel
    bf16x8 qf0 = *(const bf16x8*)(Qg + (size_t)l15 * QKW + quad * 8);
    bf16x8 qf1 = *(const bf16x8*)(Qg + (size_t)l15 * QKW + 32 + quad * 8);

// stage one 64x64 bf16 tile (512 x 16B chunks, 2/thread) with source-side
// XOR swizzle: LDS chunk (row, c') holds global chunk (row, c'^(row&7))
#define STAGE_K(j, buf) do {                                                  \
    _Pragma("unroll")                                                         \
    for (int p = 0; p < 2; ++p) {                                             \
        int ci = tid + p * 256;                                               \
        int row_ = ci >> 3;                                                   \
        int sc_  = (ci & 7) ^ (row_ & 7);                                     \
        g2l16(Kg + (size_t)((j) * 64 + row_) * QKW + sc_ * 8,                 \
              (unsigned short*)&Ks[buf][ci * 8]);                             \
    } } while (0)

#define STAGE_V(j, buf) do {                                                  \
    _Pragma("unroll")                                                         \
    for (int p = 0; p < 2; ++p) {                                             \
        int ci = tid + p * 256;                                               \
        int row_ = ci >> 3;                                                   \
        int sc_  = (ci & 7) ^ (row_ & 7);                                     \
        g2l16(Vg + (size_t)row_ * SS + (j) * 64 + sc_ * 8,                    \
              (unsigned short*)&Vs[buf][ci * 8]);                             \
    } } while (0)

    // ---------------- pass 1: l ----------------
    float lpa[4] = {0.f, 0.f, 0.f, 0.f};
    STAGE_K(0, 0);
    __syncthreads();
    int cur = 0;
    for (int j = 0; j <= qt; ++j) {
        if (j < qt) STAGE_K(j + 1, cur ^ 1);
        const short* Kb = Ks[cur];
        const bool diag = (j == qt);

        f32x4 acc[4] = {};
        #pragma unroll
        for (int nb = 0; nb < 4; ++nb) {
            if (diag && nb > wave) continue;
            int row = nb * 16 + l15, sw = row & 7;
            bf16x8 a0 = *(const bf16x8*)(Kb + row * 64 + ((quad ^ sw) * 8));
            bf16x8 a1 = *(const bf16x8*)(Kb + row * 64 + (((quad + 4) ^ sw) * 8));
            acc[nb] = __builtin_amdgcn_mfma_f32_16x16x32_bf16(a0, qf0, acc[nb], 0, 0, 0);
            acc[nb] = __builtin_amdgcn_mfma_f32_16x16x32_bf16(a1, qf1, acc[nb], 0, 0, 0);
        }
        if (!diag) {
            #pragma unroll
            for (int nb = 0; nb < 4; ++nb) {
                int rel0 = qrow - (j * 64 + nb * 16 + quad * 4);
                #pragma unroll
                for (int r = 0; r < 4; ++r)
                    lpa[r] += __expf(acc[nb][r] + bd_s[rel0 - r]);
            }
        } else {
            #pragma unroll
            for (int nb = 0; nb < 4; ++nb) {
                if (nb > wave) continue;
                #pragma unroll
                for (int r = 0; r < 4; ++r) {
                    int rel = qrow - (j * 64 + nb * 16 + quad * 4 + r);
                    if (rel >= 0) lpa[r] += __expf(acc[nb][r] + bd_s[rel]);
                }
            }
        }
        __syncthreads();
        cur ^= 1;
    }

    float lp = (lpa[0] + lpa[1]) + (lpa[2] + lpa[3]);
    lp += __shfl_xor(lp, 16, 64);
    lp += __shfl_xor(lp, 32, 64);
    const float invl = 1.f / lp;
    const float cl   = fabsf(soff[h] + 1.f) / (float)(qrow + 1) * lp;

    // ---------------- pass 2: output ----------------
    f32x4 oacc[4] = {};
    STAGE_K(0, 0);
    STAGE_V(0, 0);
    __syncthreads();
    cur = 0;
    for (int j = 0; j <= qt; ++j) {
        if (j < qt) { STAGE_K(j + 1, cur ^ 1); STAGE_V(j + 1, cur ^ 1); }
        const short* Kb = Ks[cur];
        const short* Vb = Vs[cur];
        const bool diag = (j == qt);

        f32x4 acc[4] = {};
        #pragma unroll
        for (int nb = 0; nb < 4; ++nb) {
            if (diag && nb > wave) continue;
            int row = nb * 16 + l15, sw = row & 7;
            bf16x8 a0 = *(const bf16x8*)(Kb + row * 64 + ((quad ^ sw) * 8));
            bf16x8 a1 = *(const bf16x8*)(Kb + row * 64 + (((quad + 4) ^ sw) * 8));
            acc[nb] = __builtin_amdgcn_mfma_f32_16x16x32_bf16(a0, qf0, acc[nb], 0, 0, 0);
            acc[nb] = __builtin_amdgcn_mfma_f32_16x16x32_bf16(a1, qf1, acc[nb], 0, 0, 0);
        }

        // w = relu(exp(s + bias) - cl) for this lane's q=l15, kpos quad*4+r
        unsigned int pk[4][2];
        #pragma unroll
        for (int nb = 0; nb < 4; ++nb) {
            float w[4];
            #pragma unroll
            for (int r = 0; r < 4; ++r) {
                int rel = qrow - (j * 64 + nb * 16 + quad * 4 + r);
                float e = 0.f;
                if (rel >= 0)
                    e = fmaxf(__expf(acc[nb][r] + bd_s[rel]) - cl, 0.f);
                w[r] = e;
            }
            asm("v_cvt_pk_bf16_f32 %0, %1, %2" : "=v"(pk[nb][0]) : "v"(w[0]), "v"(w[1]));
            asm("v_cvt_pk_bf16_f32 %0, %1, %2" : "=v"(pk[nb][1]) : "v"(w[2]), "v"(w[3]));
        }
        unsigned int ppk[4][2];
        #pragma unroll
        for (int nb = 0; nb < 4; ++nb) {
            ppk[nb][0] = __shfl_xor(pk[nb][0], 16, 64);
            ppk[nb][1] = __shfl_xor(pk[nb][1], 16, 64);
        }

        // PV with permuted k-slots: slot quad*8+e <-> kpos 16*(2s+(quad&1)) +
        // 8*(quad>>1) + e; V read at the same permuted (swizzled) chunk.
        const bool oddq = quad & 1;
        const int  cv   = ((quad & 1) << 1) | (quad >> 1);   // 0,2,1,3
        #pragma unroll
        for (int s = 0; s < 2; ++s) {
            if (diag && s == 1 && wave < 2) continue;   // dead kpos block
            unsigned int w0 = oddq ? ppk[2 * s + 1][0] : pk[2 * s][0];
            unsigned int w1 = oddq ? ppk[2 * s + 1][1] : pk[2 * s][1];
            unsigned int w2 = oddq ? pk[2 * s + 1][0]  : ppk[2 * s][0];
            unsigned int w3 = oddq ? pk[2 * s + 1][1]  : ppk[2 * s][1];
            u32x4 t; t[0] = w0; t[1] = w1; t[2] = w2; t[3] = w3;
            bf16x8 pf = __builtin_bit_cast(bf16x8, t);
            #pragma unroll
            for (int nd = 0; nd < 4; ++nd) {
                int rowv = nd * 16 + l15, swv = rowv & 7;
                bf16x8 vf = *(const bf16x8*)(Vb + rowv * 64 + (((cv + 4 * s) ^ swv) * 8));
                oacc[nd] = __builtin_amdgcn_mfma_f32_16x16x32_bf16(pf, vf, oacc[nd], 0, 0, 0);
            }
        }
        __syncthreads();
        cur ^= 1;
    }

    // invl for this lane's OUTPUT rows (q-sub = quad*4+r)
    float invl_r[4];
    #pragma unroll
    for (int r = 0; r < 4; ++r)
        invl_r[r] = __shfl(invl, quad * 4 + r, 64);

    unsigned short* aop = AO + (size_t)(b * SS + q0 + wave * 16 + quad * 4) * 2048
                             + h * 64 + l15;
    #pragma unroll
    for (int nd = 0; nd < 4; ++nd)
        #pragma unroll
        for (int r = 0; r < 4; ++r)
            aop[(size_t)r * 2048 + nd * 16] = f2bf(oacc[nd][r] * invl_r[r]);
#undef STAGE_K
#undef STAGE_V
}

// ---------------------------------------------------------------------------
extern "C" void kernel_launch(void* const* d_in, const int* in_sizes, int n_in,
                              void* d_out, int out_size, void* d_ws, size_t ws_size,
                              hipStream_t stream)
{
    const float* hidden    = (const float*)d_in[0];
    const float* Wq        = (const float*)d_in[2];
    const float* Wk        = (const float*)d_in[3];
    const float* Wv        = (const float*)d_in[4];
    const float* Wo        = (const float*)d_in[5];
    const float* bias_diag = (const float*)d_in[6];
    const float* soff      = (const float*)d_in[7];
    float* out = (float*)d_out;

    // Workspace aliasing:
    //  A [0,20.97M): hidden_bf(8.39) + WqkvT(12.58) -- inputs of QKV gemm.
    //                AO_bf at [12.58M..) only AFTER WqkvT is dead (attention
    //                writes AO_bf after the QKV gemm consumed WqkvT).
    //  B [20.97M,29.36M): WoT
    //  C [29.36M,41.94M): qk_bf(10.49M) + v_t(2.10M)
    char* wsb = (char*)d_ws;
    unsigned short* hidden_bf = (unsigned short*)wsb;
    unsigned short* WqkvT     = (unsigned short*)(wsb + (size_t)8388608);
    unsigned short* AO_bf     = (unsigned short*)(wsb + (size_t)12582912);
    unsigned short* WoT       = (unsigned short*)(wsb + (size_t)20971520);
    unsigned short* qk_bf     = (unsigned short*)(wsb + (size_t)29360128);
    unsigned short* v_t       = (unsigned short*)(wsb + (size_t)29360128 + (size_t)2048 * 2560 * 2);

    // 1. weight transposes + hidden convert (one launch, vectorized)
    prep<<<dim3(32, 32, 5), dim3(256), 0, stream>>>(
        hidden, Wq, Wk, Wv, Wo, hidden_bf, WqkvT, WoT);

    // 2. fused QKV projection + rope/V-transpose epilogue
    gemm_qkv_fused<<<dim3(48, 16), dim3(256), 0, stream>>>(
        hidden_bf, WqkvT, qk_bf, v_t);

    // 3. two-pass LDS-staged (double-buffered, swizzled) MFMA attention
    attn_mfma<<<dim3(16, HH, BB), dim3(256), 0, stream>>>(
        qk_bf, v_t, bias_diag, soff, AO_bf);

    // 4. output projection
    gemm_bf16_bt<<<dim3(2048 / 64, 2048 / 128), dim3(256), 0, stream>>>(
        AO_bf, WoT, out, 2048, 2048, 2048);
}

// Round 3
// 247.684 us; speedup vs baseline: 1.5027x; 1.0666x over previous
//
#include <hip/hip_runtime.h>
#include <cstdint>
#include <cstddef>

// Problem constants
#define BB   2
#define SS   1024
#define HID  2048
#define HH   32
#define KVHH 8
#define DD   64
#define NQKV 3072   // fused QKV projection width: 2048 q + 512 k + 512 v
#define QKW  2560   // qk_bf row width: 2048 q + 512 k

typedef __attribute__((ext_vector_type(8))) short bf16x8;
typedef __attribute__((ext_vector_type(4))) float f32x4;
typedef __attribute__((ext_vector_type(4))) unsigned int u32x4;

__device__ __forceinline__ unsigned short f2bf(float f) {
    unsigned int u = __float_as_uint(f);
    unsigned int r = (u + 0x7fffu + ((u >> 16) & 1u)) >> 16;
    return (unsigned short)r;
}

// async global->LDS 16B (wave-uniform LDS base + lane*16 layout required)
__device__ __forceinline__ void g2l16(const unsigned short* g, unsigned short* l) {
    __builtin_amdgcn_global_load_lds(
        (__attribute__((address_space(1))) void*)(unsigned short*)g,
        (__attribute__((address_space(3))) void*)l,
        16, 0, 0);
}

// ---------------------------------------------------------------------------
// prep (vectorized): z=0..3 weight transpose+convert (64x64 tiles, float4
// reads, ushort4 writes); z=4 hidden fp32->bf16 straight convert.
// ---------------------------------------------------------------------------
__global__ __launch_bounds__(256) void prep(
    const float* __restrict__ hidden,
    const float* __restrict__ Wq, const float* __restrict__ Wk,
    const float* __restrict__ Wv, const float* __restrict__ Wo,
    unsigned short* __restrict__ hidden_bf,
    unsigned short* __restrict__ WqkvT,
    unsigned short* __restrict__ WoT)
{
    const int z   = blockIdx.z;
    const int tid = threadIdx.x;

    if (z == 4) {   // hidden convert, 2048x2048, 64x64 tile
        int r0 = blockIdx.y * 64, c0 = blockIdx.x * 64;
        #pragma unroll
        for (int p = 0; p < 4; ++p) {
            int f = tid + p * 256;            // 0..1023
            int row = r0 + (f >> 4), c4 = c0 + (f & 15) * 4;
            float4 v = *(const float4*)&hidden[(size_t)row * 2048 + c4];
            ushort4 o;
            o.x = f2bf(v.x); o.y = f2bf(v.y); o.z = f2bf(v.z); o.w = f2bf(v.w);
            *(ushort4*)&hidden_bf[(size_t)row * 2048 + c4] = o;
        }
        return;
    }

    const float* W;
    unsigned short* Wt;
    int N;
    if (z == 0)      { W = Wq; Wt = WqkvT;                        N = 2048; }
    else if (z == 1) { W = Wk; Wt = WqkvT + (size_t)2048 * 2048;  N = 512;  }
    else if (z == 2) { W = Wv; Wt = WqkvT + (size_t)2560 * 2048;  N = 512;  }
    else             { W = Wo; Wt = WoT;                          N = 2048; }
    if (blockIdx.x * 64 >= N) return;

    // 64x64 transpose tile via LDS, stride 68 (2-way bank alias only)
    __shared__ float t[64][68];
    const int n0 = blockIdx.x * 64, k0 = blockIdx.y * 64;
    #pragma unroll
    for (int p = 0; p < 4; ++p) {
        int f = tid + p * 256;
        int row = f >> 4, c4 = (f & 15) * 4;     // row=k_local, c4=n_local
        float4 v = *(const float4*)&W[(size_t)(k0 + row) * N + n0 + c4];
        t[row][c4 + 0] = v.x; t[row][c4 + 1] = v.y;
        t[row][c4 + 2] = v.z; t[row][c4 + 3] = v.w;
    }
    __syncthreads();
    #pragma unroll
    for (int p = 0; p < 4; ++p) {
        int f = tid + p * 256;
        int nrow = f >> 4, kc4 = (f & 15) * 4;   // output row=n, col=k
        ushort4 o;
        o.x = f2bf(t[kc4 + 0][nrow]);
        o.y = f2bf(t[kc4 + 1][nrow]);
        o.z = f2bf(t[kc4 + 2][nrow]);
        o.w = f2bf(t[kc4 + 3][nrow]);
        *(ushort4*)&Wt[(size_t)(n0 + nrow) * 2048 + k0 + kc4] = o;
    }
}

// ---------------------------------------------------------------------------
// Fused QKV GEMM + rope/V-transpose epilogue. Tile 128(M) x 64(N), BK=32,
// async global_load_lds staging. Grid (48, 16): bx<32 -> q head bx;
// bx 32..39 -> k head bx-32; bx 40..47 -> v head bx-40.
// ---------------------------------------------------------------------------
__global__ __launch_bounds__(256) void gemm_qkv_fused(
    const unsigned short* __restrict__ A,     // hidden_bf [2048][2048]
    const unsigned short* __restrict__ Bt,    // WqkvT [3072][2048]
    unsigned short* __restrict__ qk_bf,       // [2048][2560]
    unsigned short* __restrict__ v_t)         // [1024][1024]
{
    __shared__ short As[128][32];   // 8 KB
    __shared__ short Bs[64][32];    // 4 KB
    __shared__ float Ct[128][65];   // 32.5 KB

    const int tid  = threadIdx.x;
    const int lane = tid & 63;
    const int wave = tid >> 6;
    const int wm = (wave >> 1) * 64, wn = (wave & 1) * 32;
    const int m0 = blockIdx.y * 128, n0 = blockIdx.x * 64;
    const int K = 2048;

    f32x4 acc[4][2] = {};

    const int mrow = lane & 15;
    const int kq   = (lane >> 4) * 8;
    const int quad = lane >> 4;
    const int l15  = lane & 15;

    for (int k0 = 0; k0 < K; k0 += 32) {
        #pragma unroll
        for (int p = 0; p < 2; ++p) {   // A: 512 x 16B chunks
            int ci = tid + p * 256;
            int row = ci >> 2;
            int q = (ci & 3) * 8;
            g2l16(&A[(size_t)(m0 + row) * K + k0 + q],
                  (unsigned short*)&As[0][0] + ci * 8);
        }
        {   // B: 256 x 16B chunks
            int ci = tid;
            int row = ci >> 2;
            int q = (ci & 3) * 8;
            g2l16(&Bt[(size_t)(n0 + row) * K + k0 + q],
                  (unsigned short*)&Bs[0][0] + ci * 8);
        }
        __syncthreads();

        bf16x8 af[4], bfr[2];
        #pragma unroll
        for (int i = 0; i < 4; ++i)
            af[i] = *(const bf16x8*)&As[wm + i * 16 + mrow][kq];
        #pragma unroll
        for (int j = 0; j < 2; ++j)
            bfr[j] = *(const bf16x8*)&Bs[wn + j * 16 + mrow][kq];

        #pragma unroll
        for (int i = 0; i < 4; ++i)
            #pragma unroll
            for (int j = 0; j < 2; ++j)
                acc[i][j] = __builtin_amdgcn_mfma_f32_16x16x32_bf16(
                    af[i], bfr[j], acc[i][j], 0, 0, 0);
        __syncthreads();
    }

    // ---- epilogue: fragments -> LDS fp32 tile ----
    #pragma unroll
    for (int i = 0; i < 4; ++i)
        #pragma unroll
        for (int j = 0; j < 2; ++j)
            #pragma unroll
            for (int rg = 0; rg < 4; ++rg)
                Ct[wm + i * 16 + quad * 4 + rg][wn + j * 16 + l15] = acc[i][j][rg];
    __syncthreads();

    const int bx = blockIdx.x;
    const int b  = m0 >> 10;           // batch (tile never straddles)
    const int s0 = m0 & 1023;

    if (bx < 40) {
        // rope q/k: qk_bf col base = bx*64 (q: 0..2047; k: 2048 + (bx-32)*64)
        const int hc = bx * 64;
        const float scale = (bx < 32) ? 0.125f : 1.0f;
        #pragma unroll
        for (int p = 0; p < 4; ++p) {
            int idx = tid + p * 256;          // 128 rows x 8 t-groups
            int row = idx >> 3, t0 = (idx & 7) * 4;
            int s = s0 + row;
            ushort4 o1, o2;
            #pragma unroll
            for (int k = 0; k < 4; ++k) {
                int t = t0 + k;
                float x1 = Ct[row][t];
                float x2 = Ct[row][t + 32];
                float inv = __expf(-(float)t * 0.28782313662425572f);
                float ang = (float)s * inv;
                float c  = __cosf(ang);
                float sn = __sinf(ang);
                ((unsigned short*)&o1)[k] = f2bf((x1 * c - x2 * sn) * scale);
                ((unsigned short*)&o2)[k] = f2bf((x2 * c + x1 * sn) * scale);
            }
            unsigned short* dst = qk_bf + (size_t)(m0 + row) * QKW + hc;
            *(ushort4*)&dst[t0]      = o1;
            *(ushort4*)&dst[t0 + 32] = o2;
        }
    } else {
        // v transpose: v_t[(b*512 + (bx-40)*64 + c)][s0 + srow]
        const int vb = b * 512 + (bx - 40) * 64;
        #pragma unroll
        for (int p = 0; p < 8; ++p) {
            int idx = tid + p * 256;          // 64 c x 32 s-groups
            int c = idx >> 5, srow = (idx & 31) * 4;
            ushort4 o;
            #pragma unroll
            for (int k = 0; k < 4; ++k)
                ((unsigned short*)&o)[k] = f2bf(Ct[srow + k][c]);
            *(ushort4*)&v_t[(size_t)(vb + c) * 1024 + s0 + srow] = o;
        }
    }
}

// ---------------------------------------------------------------------------
// bf16 MFMA GEMM, B-transposed (Wo projection). Tile 128x64, BK=32.
// ---------------------------------------------------------------------------
__global__ __launch_bounds__(256) void gemm_bf16_bt(
    const unsigned short* __restrict__ A,
    const unsigned short* __restrict__ Bt,
    float* __restrict__ C, int M, int N, int K)
{
    __shared__ short As[128][32];   // 8 KB
    __shared__ short Bs[64][32];    // 4 KB

    const int tid  = threadIdx.x;
    const int lane = tid & 63;
    const int wave = tid >> 6;
    const int wm = (wave >> 1) * 64, wn = (wave & 1) * 32;
    const int m0 = blockIdx.y * 128, n0 = blockIdx.x * 64;

    f32x4 acc[4][2] = {};

    const int mrow = lane & 15;
    const int kq   = (lane >> 4) * 8;

    for (int k0 = 0; k0 < K; k0 += 32) {
        #pragma unroll
        for (int p = 0; p < 2; ++p) {   // A: 512 x 16B chunks
            int ci = tid + p * 256;
            int row = ci >> 2;
            int q = (ci & 3) * 8;
            g2l16(&A[(size_t)(m0 + row) * K + k0 + q],
                  (unsigned short*)&As[0][0] + ci * 8);
        }
        {   // B: 256 x 16B chunks
            int ci = tid;
            int row = ci >> 2;
            int q = (ci & 3) * 8;
            g2l16(&Bt[(size_t)(n0 + row) * K + k0 + q],
                  (unsigned short*)&Bs[0][0] + ci * 8);
        }
        __syncthreads();

        bf16x8 af[4], bfr[2];
        #pragma unroll
        for (int i = 0; i < 4; ++i)
            af[i] = *(const bf16x8*)&As[wm + i * 16 + mrow][kq];
        #pragma unroll
        for (int j = 0; j < 2; ++j)
            bfr[j] = *(const bf16x8*)&Bs[wn + j * 16 + mrow][kq];

        #pragma unroll
        for (int i = 0; i < 4; ++i)
            #pragma unroll
            for (int j = 0; j < 2; ++j)
                acc[i][j] = __builtin_amdgcn_mfma_f32_16x16x32_bf16(
                    af[i], bfr[j], acc[i][j], 0, 0, 0);
        __syncthreads();
    }

    #pragma unroll
    for (int i = 0; i < 4; ++i) {
        int grow = m0 + wm + i * 16 + (lane >> 4) * 4;
        #pragma unroll
        for (int j = 0; j < 2; ++j) {
            int gcol = n0 + wn + j * 16 + (lane & 15);
            #pragma unroll
            for (int rg = 0; rg < 4; ++rg)
                C[(size_t)(grow + rg) * N + gcol] = acc[i][j][rg];
        }
    }
}

// ---------------------------------------------------------------------------
// MFMA flash attention, two-pass. Swapped-operand QK^T, in-register P->PV,
// double-buffered swizzled global_load_lds staging (verified r2).
// r3 change: 1D grid (1024 blocks) with a balanced qt permutation.
// CU(id) = id mod 256, so a CU's 4 blocks have v=(id>>6)&15 in one residue
// class mod 4; qtab maps each class {v,v+4,v+8,v+12} to qt sets summing to
// 30 ({15,10,4,1},{14,11,5,0},{13,8,6,3},{12,9,7,2}) -> every CU carries
// ~equal tile-units (was 16..64, 16:1 imbalance with qt = 15-blockIdx.x).
// ---------------------------------------------------------------------------
__global__ __launch_bounds__(256, 4) void attn_mfma(
    const unsigned short* __restrict__ qk_bf,   // [2048][2560]
    const unsigned short* __restrict__ v_t,     // [1024][1024]
    const float* __restrict__ bias_diag,
    const float* __restrict__ soff,
    unsigned short* __restrict__ AO)            // [2048][2048] bf16
{
    static const unsigned char qtab[16] =
        {15, 14, 13, 12, 10, 11, 8, 9, 4, 5, 6, 7, 1, 0, 3, 2};
    const int id = (int)blockIdx.x;
    const int qt = qtab[(id >> 6) & 15];
    const int h  = id & 31;
    const int b  = (id >> 5) & 1;
    const int kh = h >> 2;
    const int tid  = threadIdx.x;
    const int lane = tid & 63;
    const int wave = tid >> 6;
    const int quad = lane >> 4;
    const int l15  = lane & 15;
    const int q0   = qt * 64;

    __shared__ short Ks[2][4096];   // [64 rows][64 cols] bf16, chunk-swizzled
    __shared__ short Vs[2][4096];   // [64 d][64 k] bf16, chunk-swizzled
    __shared__ float bd_s[1024];

    for (int i = tid; i < 1024; i += 256) bd_s[i] = bias_diag[h * 1024 + i];

    const unsigned short* Qg = qk_bf + (size_t)(b * SS + q0 + wave * 16) * QKW + h * 64;
    const unsigned short* Kg = qk_bf + (size_t)(b * SS) * QKW + 2048 + kh * 64;
    const unsigned short* Vg = v_t + (size_t)(b * 512 + kh * 64) * SS;

    const int qrow = q0 + wave * 16 + l15;      // this lane's q (S^T column)

    // Q fragments (B operand), hoisted for the whole kernel
    bf16x8 qf0 = *(const bf16x8*)(Qg + (size_t)l15 * QKW + quad * 8);
    bf16x8 qf1 = *(const bf16x8*)(Qg + (size_t)l15 * QKW + 32 + quad * 8);

// stage one 64x64 bf16 tile (512 x 16B chunks, 2/thread) with source-side
// XOR swizzle: LDS chunk (row, c') holds global chunk (row, c'^(row&7))
#define STAGE_K(j, buf) do {                                                  \
    _Pragma("unroll")                                                         \
    for (int p = 0; p < 2; ++p) {                                             \
        int ci = tid + p * 256;                                               \
        int row_ = ci >> 3;                                                   \
        int sc_  = (ci & 7) ^ (row_ & 7);                                     \
        g2l16(Kg + (size_t)((j) * 64 + row_) * QKW + sc_ * 8,                 \
              (unsigned short*)&Ks[buf][ci * 8]);                             \
    } } while (0)

#define STAGE_V(j, buf) do {                                                  \
    _Pragma("unroll")                                                         \
    for (int p = 0; p < 2; ++p) {                                             \
        int ci = tid + p * 256;                                               \
        int row_ = ci >> 3;                                                   \
        int sc_  = (ci & 7) ^ (row_ & 7);                                     \
        g2l16(Vg + (size_t)row_ * SS + (j) * 64 + sc_ * 8,                    \
              (unsigned short*)&Vs[buf][ci * 8]);                             \
    } } while (0)

    // ---------------- pass 1: l ----------------
    float lpa[4] = {0.f, 0.f, 0.f, 0.f};
    STAGE_K(0, 0);
    __syncthreads();
    int cur = 0;
    for (int j = 0; j <= qt; ++j) {
        if (j < qt) STAGE_K(j + 1, cur ^ 1);
        const short* Kb = Ks[cur];
        const bool diag = (j == qt);

        f32x4 acc[4] = {};
        #pragma unroll
        for (int nb = 0; nb < 4; ++nb) {
            if (diag && nb > wave) continue;
            int row = nb * 16 + l15, sw = row & 7;
            bf16x8 a0 = *(const bf16x8*)(Kb + row * 64 + ((quad ^ sw) * 8));
            bf16x8 a1 = *(const bf16x8*)(Kb + row * 64 + (((quad + 4) ^ sw) * 8));
            acc[nb] = __builtin_amdgcn_mfma_f32_16x16x32_bf16(a0, qf0, acc[nb], 0, 0, 0);
            acc[nb] = __builtin_amdgcn_mfma_f32_16x16x32_bf16(a1, qf1, acc[nb], 0, 0, 0);
        }
        if (!diag) {
            #pragma unroll
            for (int nb = 0; nb < 4; ++nb) {
                int rel0 = qrow - (j * 64 + nb * 16 + quad * 4);
                #pragma unroll
                for (int r = 0; r < 4; ++r)
                    lpa[r] += __expf(acc[nb][r] + bd_s[rel0 - r]);
            }
        } else {
            #pragma unroll
            for (int nb = 0; nb < 4; ++nb) {
                if (nb > wave) continue;
                #pragma unroll
                for (int r = 0; r < 4; ++r) {
                    int rel = qrow - (j * 64 + nb * 16 + quad * 4 + r);
                    if (rel >= 0) lpa[r] += __expf(acc[nb][r] + bd_s[rel]);
                }
            }
        }
        __syncthreads();
        cur ^= 1;
    }

    float lp = (lpa[0] + lpa[1]) + (lpa[2] + lpa[3]);
    lp += __shfl_xor(lp, 16, 64);
    lp += __shfl_xor(lp, 32, 64);
    const float invl = 1.f / lp;
    const float cl   = fabsf(soff[h] + 1.f) / (float)(qrow + 1) * lp;

    // ---------------- pass 2: output ----------------
    f32x4 oacc[4] = {};
    STAGE_K(0, 0);
    STAGE_V(0, 0);
    __syncthreads();
    cur = 0;
    for (int j = 0; j <= qt; ++j) {
        if (j < qt) { STAGE_K(j + 1, cur ^ 1); STAGE_V(j + 1, cur ^ 1); }
        const short* Kb = Ks[cur];
        const short* Vb = Vs[cur];
        const bool diag = (j == qt);

        f32x4 acc[4] = {};
        #pragma unroll
        for (int nb = 0; nb < 4; ++nb) {
            if (diag && nb > wave) continue;
            int row = nb * 16 + l15, sw = row & 7;
            bf16x8 a0 = *(const bf16x8*)(Kb + row * 64 + ((quad ^ sw) * 8));
            bf16x8 a1 = *(const bf16x8*)(Kb + row * 64 + (((quad + 4) ^ sw) * 8));
            acc[nb] = __builtin_amdgcn_mfma_f32_16x16x32_bf16(a0, qf0, acc[nb], 0, 0, 0);
            acc[nb] = __builtin_amdgcn_mfma_f32_16x16x32_bf16(a1, qf1, acc[nb], 0, 0, 0);
        }

        // w = relu(exp(s + bias) - cl) for this lane's q=l15, kpos quad*4+r
        unsigned int pk[4][2];
        #pragma unroll
        for (int nb = 0; nb < 4; ++nb) {
            float w[4];
            #pragma unroll
            for (int r = 0; r < 4; ++r) {
                int rel = qrow - (j * 64 + nb * 16 + quad * 4 + r);
                float e = 0.f;
                if (rel >= 0)
                    e = fmaxf(__expf(acc[nb][r] + bd_s[rel]) - cl, 0.f);
                w[r] = e;
            }
            asm("v_cvt_pk_bf16_f32 %0, %1, %2" : "=v"(pk[nb][0]) : "v"(w[0]), "v"(w[1]));
            asm("v_cvt_pk_bf16_f32 %0, %1, %2" : "=v"(pk[nb][1]) : "v"(w[2]), "v"(w[3]));
        }
        unsigned int ppk[4][2];
        #pragma unroll
        for (int nb = 0; nb < 4; ++nb) {
            ppk[nb][0] = __shfl_xor(pk[nb][0], 16, 64);
            ppk[nb][1] = __shfl_xor(pk[nb][1], 16, 64);
        }

        // PV with permuted k-slots: slot quad*8+e <-> kpos 16*(2s+(quad&1)) +
        // 8*(quad>>1) + e; V read at the same permuted (swizzled) chunk.
        const bool oddq = quad & 1;
        const int  cv   = ((quad & 1) << 1) | (quad >> 1);   // 0,2,1,3
        #pragma unroll
        for (int s = 0; s < 2; ++s) {
            if (diag && s == 1 && wave < 2) continue;   // dead kpos block
            unsigned int w0 = oddq ? ppk[2 * s + 1][0] : pk[2 * s][0];
            unsigned int w1 = oddq ? ppk[2 * s + 1][1] : pk[2 * s][1];
            unsigned int w2 = oddq ? pk[2 * s + 1][0]  : ppk[2 * s][0];
            unsigned int w3 = oddq ? pk[2 * s + 1][1]  : ppk[2 * s][1];
            u32x4 t; t[0] = w0; t[1] = w1; t[2] = w2; t[3] = w3;
            bf16x8 pf = __builtin_bit_cast(bf16x8, t);
            #pragma unroll
            for (int nd = 0; nd < 4; ++nd) {
                int rowv = nd * 16 + l15, swv = rowv & 7;
                bf16x8 vf = *(const bf16x8*)(Vb + rowv * 64 + (((cv + 4 * s) ^ swv) * 8));
                oacc[nd] = __builtin_amdgcn_mfma_f32_16x16x32_bf16(pf, vf, oacc[nd], 0, 0, 0);
            }
        }
        __syncthreads();
        cur ^= 1;
    }

    // invl for this lane's OUTPUT rows (q-sub = quad*4+r)
    float invl_r[4];
    #pragma unroll
    for (int r = 0; r < 4; ++r)
        invl_r[r] = __shfl(invl, quad * 4 + r, 64);

    unsigned short* aop = AO + (size_t)(b * SS + q0 + wave * 16 + quad * 4) * 2048
                             + h * 64 + l15;
    #pragma unroll
    for (int nd = 0; nd < 4; ++nd)
        #pragma unroll
        for (int r = 0; r < 4; ++r)
            aop[(size_t)r * 2048 + nd * 16] = f2bf(oacc[nd][r] * invl_r[r]);
#undef STAGE_K
#undef STAGE_V
}

// ---------------------------------------------------------------------------
extern "C" void kernel_launch(void* const* d_in, const int* in_sizes, int n_in,
                              void* d_out, int out_size, void* d_ws, size_t ws_size,
                              hipStream_t stream)
{
    const float* hidden    = (const float*)d_in[0];
    const float* Wq        = (const float*)d_in[2];
    const float* Wk        = (const float*)d_in[3];
    const float* Wv        = (const float*)d_in[4];
    const float* Wo        = (const float*)d_in[5];
    const float* bias_diag = (const float*)d_in[6];
    const float* soff      = (const float*)d_in[7];
    float* out = (float*)d_out;

    // Workspace aliasing:
    //  A [0,20.97M): hidden_bf(8.39) + WqkvT(12.58) -- inputs of QKV gemm.
    //                AO_bf at [12.58M..) only AFTER WqkvT is dead (attention
    //                writes AO_bf after the QKV gemm consumed WqkvT).
    //  B [20.97M,29.36M): WoT
    //  C [29.36M,41.94M): qk_bf(10.49M) + v_t(2.10M)
    char* wsb = (char*)d_ws;
    unsigned short* hidden_bf = (unsigned short*)wsb;
    unsigned short* WqkvT     = (unsigned short*)(wsb + (size_t)8388608);
    unsigned short* AO_bf     = (unsigned short*)(wsb + (size_t)12582912);
    unsigned short* WoT       = (unsigned short*)(wsb + (size_t)20971520);
    unsigned short* qk_bf     = (unsigned short*)(wsb + (size_t)29360128);
    unsigned short* v_t       = (unsigned short*)(wsb + (size_t)29360128 + (size_t)2048 * 2560 * 2);

    // 1. weight transposes + hidden convert (one launch, vectorized)
    prep<<<dim3(32, 32, 5), dim3(256), 0, stream>>>(
        hidden, Wq, Wk, Wv, Wo, hidden_bf, WqkvT, WoT);

    // 2. fused QKV projection + rope/V-transpose epilogue
    gemm_qkv_fused<<<dim3(48, 16), dim3(256), 0, stream>>>(
        hidden_bf, WqkvT, qk_bf, v_t);

    // 3. two-pass LDS-staged MFMA attention, balanced 1D grid
    attn_mfma<<<dim3(1024), dim3(256), 0, stream>>>(
        qk_bf, v_t, bias_diag, soff, AO_bf);

    // 4. output projection
    gemm_bf16_bt<<<dim3(2048 / 64, 2048 / 128), dim3(256), 0, stream>>>(
        AO_bf, WoT, out, 2048, 2048, 2048);
}

// Round 4
// 230.020 us; speedup vs baseline: 1.6181x; 1.0768x over previous
//
#include <hip/hip_runtime.h>
#include <cstdint>
#include <cstddef>

// Problem constants
#define BB   2
#define SS   1024
#define HID  2048
#define HH   32
#define KVHH 8
#define DD   64
#define NQKV 3072   // fused QKV projection width: 2048 q + 512 k + 512 v
#define QKW  2560   // qk_bf row width: 2048 q + 512 k

typedef __attribute__((ext_vector_type(8))) short bf16x8;
typedef __attribute__((ext_vector_type(4))) float f32x4;
typedef __attribute__((ext_vector_type(4))) unsigned int u32x4;

__device__ __forceinline__ unsigned short f2bf(float f) {
    unsigned int u = __float_as_uint(f);
    unsigned int r = (u + 0x7fffu + ((u >> 16) & 1u)) >> 16;
    return (unsigned short)r;
}

// async global->LDS 16B (wave-uniform LDS base + lane*16 layout required)
__device__ __forceinline__ void g2l16(const unsigned short* g, unsigned short* l) {
    __builtin_amdgcn_global_load_lds(
        (__attribute__((address_space(1))) void*)(unsigned short*)g,
        (__attribute__((address_space(3))) void*)l,
        16, 0, 0);
}

// ---------------------------------------------------------------------------
// prep (vectorized): z=0..3 weight transpose+convert (64x64 tiles, float4
// reads, ushort4 writes); z=4 hidden fp32->bf16 straight convert.
// ---------------------------------------------------------------------------
__global__ __launch_bounds__(256) void prep(
    const float* __restrict__ hidden,
    const float* __restrict__ Wq, const float* __restrict__ Wk,
    const float* __restrict__ Wv, const float* __restrict__ Wo,
    unsigned short* __restrict__ hidden_bf,
    unsigned short* __restrict__ WqkvT,
    unsigned short* __restrict__ WoT)
{
    const int z   = blockIdx.z;
    const int tid = threadIdx.x;

    if (z == 4) {   // hidden convert, 2048x2048, 64x64 tile
        int r0 = blockIdx.y * 64, c0 = blockIdx.x * 64;
        #pragma unroll
        for (int p = 0; p < 4; ++p) {
            int f = tid + p * 256;            // 0..1023
            int row = r0 + (f >> 4), c4 = c0 + (f & 15) * 4;
            float4 v = *(const float4*)&hidden[(size_t)row * 2048 + c4];
            ushort4 o;
            o.x = f2bf(v.x); o.y = f2bf(v.y); o.z = f2bf(v.z); o.w = f2bf(v.w);
            *(ushort4*)&hidden_bf[(size_t)row * 2048 + c4] = o;
        }
        return;
    }

    const float* W;
    unsigned short* Wt;
    int N;
    if (z == 0)      { W = Wq; Wt = WqkvT;                        N = 2048; }
    else if (z == 1) { W = Wk; Wt = WqkvT + (size_t)2048 * 2048;  N = 512;  }
    else if (z == 2) { W = Wv; Wt = WqkvT + (size_t)2560 * 2048;  N = 512;  }
    else             { W = Wo; Wt = WoT;                          N = 2048; }
    if (blockIdx.x * 64 >= N) return;

    // 64x64 transpose tile via LDS, stride 68 (2-way bank alias only)
    __shared__ float t[64][68];
    const int n0 = blockIdx.x * 64, k0 = blockIdx.y * 64;
    #pragma unroll
    for (int p = 0; p < 4; ++p) {
        int f = tid + p * 256;
        int row = f >> 4, c4 = (f & 15) * 4;     // row=k_local, c4=n_local
        float4 v = *(const float4*)&W[(size_t)(k0 + row) * N + n0 + c4];
        t[row][c4 + 0] = v.x; t[row][c4 + 1] = v.y;
        t[row][c4 + 2] = v.z; t[row][c4 + 3] = v.w;
    }
    __syncthreads();
    #pragma unroll
    for (int p = 0; p < 4; ++p) {
        int f = tid + p * 256;
        int nrow = f >> 4, kc4 = (f & 15) * 4;   // output row=n, col=k
        ushort4 o;
        o.x = f2bf(t[kc4 + 0][nrow]);
        o.y = f2bf(t[kc4 + 1][nrow]);
        o.z = f2bf(t[kc4 + 2][nrow]);
        o.w = f2bf(t[kc4 + 3][nrow]);
        *(ushort4*)&Wt[(size_t)(n0 + nrow) * 2048 + k0 + kc4] = o;
    }
}

// ---------------------------------------------------------------------------
// Fused QKV GEMM + rope/V-transpose epilogue. Tile 128(M) x 128(N), BK=64,
// swizzled global_load_lds staging (chunk^row&7 -> 2-way-free ds_read_b128).
// 4 waves, each 64x64 (acc 4x4): 32 MFMA : 16 ds_read per K-step.
// Grid (24, 16): bx<16 -> q heads 2bx..2bx+1; 16..19 -> k; 20..23 -> v.
// Epilogue: two 64-row passes through Ct[64][129] fp32 (aliases staging LDS),
// rope'd bf16 into qk_bf (q scaled 0.125) or transposed bf16 into v_t.
// ---------------------------------------------------------------------------
__global__ __launch_bounds__(256) void gemm_qkv_fused(
    const unsigned short* __restrict__ A,     // hidden_bf [2048][2048]
    const unsigned short* __restrict__ Bt,    // WqkvT [3072][2048]
    unsigned short* __restrict__ qk_bf,       // [2048][2560]
    unsigned short* __restrict__ v_t)         // [1024][1024]
{
    __shared__ __align__(16) char smem[33024];
    short* Asb = (short*)smem;                 // [128][64] swizzled, 16 KB
    short* Bsb = (short*)(smem + 16384);       // [128][64] swizzled, 16 KB
    float* Ctf = (float*)smem;                 // [64][129] epilogue, 33 KB

    const int tid  = threadIdx.x;
    const int lane = tid & 63;
    const int wave = tid >> 6;
    const int quad = lane >> 4;
    const int l15  = lane & 15;
    const int wm = (wave >> 1) * 64, wn = (wave & 1) * 64;
    const int m0 = blockIdx.y * 128, n0 = blockIdx.x * 128;
    const int K = 2048;

    f32x4 acc[4][4] = {};

    for (int k0 = 0; k0 < K; k0 += 64) {
        #pragma unroll
        for (int p = 0; p < 4; ++p) {   // A: 1024 x 16B chunks
            int ci = tid + p * 256;
            int row = ci >> 3, sc = (ci & 7) ^ (row & 7);
            g2l16(&A[(size_t)(m0 + row) * K + k0 + sc * 8],
                  (unsigned short*)Asb + ci * 8);
        }
        #pragma unroll
        for (int p = 0; p < 4; ++p) {   // B: 1024 x 16B chunks
            int ci = tid + p * 256;
            int row = ci >> 3, sc = (ci & 7) ^ (row & 7);
            g2l16(&Bt[(size_t)(n0 + row) * K + k0 + sc * 8],
                  (unsigned short*)Bsb + ci * 8);
        }
        __syncthreads();

        #pragma unroll
        for (int s = 0; s < 2; ++s) {
            bf16x8 af[4], bfr[4];
            #pragma unroll
            for (int i = 0; i < 4; ++i) {
                int row = wm + i * 16 + l15;
                af[i] = *(const bf16x8*)(Asb + row * 64 +
                        ((((s << 2) | quad) ^ (row & 7)) * 8));
            }
            #pragma unroll
            for (int j = 0; j < 4; ++j) {
                int row = wn + j * 16 + l15;
                bfr[j] = *(const bf16x8*)(Bsb + row * 64 +
                        ((((s << 2) | quad) ^ (row & 7)) * 8));
            }
            #pragma unroll
            for (int i = 0; i < 4; ++i)
                #pragma unroll
                for (int j = 0; j < 4; ++j)
                    acc[i][j] = __builtin_amdgcn_mfma_f32_16x16x32_bf16(
                        af[i], bfr[j], acc[i][j], 0, 0, 0);
        }
        __syncthreads();
    }

    // ---- epilogue: two 64-row passes through Ct[64][129] ----
    const int bx = blockIdx.x;
    const int b  = m0 >> 10;           // batch (tile never straddles)
    const int s0 = m0 & 1023;
    const int hcg = bx * 128;          // global qk_bf col base (q/k regions)

    #pragma unroll 1
    for (int ph = 0; ph < 2; ++ph) {
        if (ph) __syncthreads();
        if ((wave >> 1) == ph) {       // waves owning rows ph*64..+63 write
            #pragma unroll
            for (int i = 0; i < 4; ++i)
                #pragma unroll
                for (int j = 0; j < 4; ++j)
                    #pragma unroll
                    for (int rg = 0; rg < 4; ++rg)
                        Ctf[(i * 16 + quad * 4 + rg) * 129 + wn + j * 16 + l15]
                            = acc[i][j][rg];
        }
        __syncthreads();

        if (bx < 20) {
            // rope q/k (two heads per tile): cols hcg + hi*64 + t
            const float scale = (bx < 16) ? 0.125f : 1.0f;
            #pragma unroll
            for (int p = 0; p < 4; ++p) {
                int idx = tid + p * 256;       // 64 rows x 2 heads x 8 tgrps
                int row = idx >> 4, hi = (idx >> 3) & 1, t0 = (idx & 7) * 4;
                int s = s0 + ph * 64 + row;
                ushort4 o1, o2;
                #pragma unroll
                for (int k = 0; k < 4; ++k) {
                    int t = t0 + k;
                    float x1 = Ctf[row * 129 + hi * 64 + t];
                    float x2 = Ctf[row * 129 + hi * 64 + t + 32];
                    float inv = __expf(-(float)t * 0.28782313662425572f);
                    float ang = (float)s * inv;
                    float c  = __cosf(ang);
                    float sn = __sinf(ang);
                    ((unsigned short*)&o1)[k] = f2bf((x1 * c - x2 * sn) * scale);
                    ((unsigned short*)&o2)[k] = f2bf((x2 * c + x1 * sn) * scale);
                }
                unsigned short* dst =
                    qk_bf + (size_t)(m0 + ph * 64 + row) * QKW + hcg + hi * 64;
                *(ushort4*)&dst[t0]      = o1;
                *(ushort4*)&dst[t0 + 32] = o2;
            }
        } else {
            // v transpose: v_t[(b*512 + (bx-20)*128 + cc)][s0 + ph*64 + srow]
            const int vb = b * 512 + (bx - 20) * 128;
            #pragma unroll
            for (int p = 0; p < 8; ++p) {
                int idx = tid + p * 256;       // 128 cc x 16 s-groups
                int cc = idx >> 4, srow = (idx & 15) * 4;
                ushort4 o;
                #pragma unroll
                for (int k = 0; k < 4; ++k)
                    ((unsigned short*)&o)[k] = f2bf(Ctf[(srow + k) * 129 + cc]);
                *(ushort4*)&v_t[(size_t)(vb + cc) * 1024 + s0 + ph * 64 + srow] = o;
            }
        }
    }
}

// ---------------------------------------------------------------------------
// bf16 MFMA GEMM, B-transposed (Wo projection). Tile 128x64, BK=64,
// swizzled staging (same 2-way-free pattern). 512 blocks = 2/CU.
// ---------------------------------------------------------------------------
__global__ __launch_bounds__(256) void gemm_bf16_bt(
    const unsigned short* __restrict__ A,
    const unsigned short* __restrict__ Bt,
    float* __restrict__ C, int M, int N, int K)
{
    __shared__ short Asb[128 * 64];   // 16 KB swizzled
    __shared__ short Bsb[64 * 64];    // 8 KB swizzled

    const int tid  = threadIdx.x;
    const int lane = tid & 63;
    const int wave = tid >> 6;
    const int quad = lane >> 4;
    const int l15  = lane & 15;
    const int wm = (wave >> 1) * 64, wn = (wave & 1) * 32;
    const int m0 = blockIdx.y * 128, n0 = blockIdx.x * 64;

    f32x4 acc[4][2] = {};

    for (int k0 = 0; k0 < K; k0 += 64) {
        #pragma unroll
        for (int p = 0; p < 4; ++p) {   // A: 1024 x 16B chunks
            int ci = tid + p * 256;
            int row = ci >> 3, sc = (ci & 7) ^ (row & 7);
            g2l16(&A[(size_t)(m0 + row) * K + k0 + sc * 8],
                  (unsigned short*)Asb + ci * 8);
        }
        #pragma unroll
        for (int p = 0; p < 2; ++p) {   // B: 512 x 16B chunks
            int ci = tid + p * 256;
            int row = ci >> 3, sc = (ci & 7) ^ (row & 7);
            g2l16(&Bt[(size_t)(n0 + row) * K + k0 + sc * 8],
                  (unsigned short*)Bsb + ci * 8);
        }
        __syncthreads();

        #pragma unroll
        for (int s = 0; s < 2; ++s) {
            bf16x8 af[4], bfr[2];
            #pragma unroll
            for (int i = 0; i < 4; ++i) {
                int row = wm + i * 16 + l15;
                af[i] = *(const bf16x8*)(Asb + row * 64 +
                        ((((s << 2) | quad) ^ (row & 7)) * 8));
            }
            #pragma unroll
            for (int j = 0; j < 2; ++j) {
                int row = wn + j * 16 + l15;
                bfr[j] = *(const bf16x8*)(Bsb + row * 64 +
                        ((((s << 2) | quad) ^ (row & 7)) * 8));
            }
            #pragma unroll
            for (int i = 0; i < 4; ++i)
                #pragma unroll
                for (int j = 0; j < 2; ++j)
                    acc[i][j] = __builtin_amdgcn_mfma_f32_16x16x32_bf16(
                        af[i], bfr[j], acc[i][j], 0, 0, 0);
        }
        __syncthreads();
    }

    #pragma unroll
    for (int i = 0; i < 4; ++i) {
        int grow = m0 + wm + i * 16 + quad * 4;
        #pragma unroll
        for (int j = 0; j < 2; ++j) {
            int gcol = n0 + wn + j * 16 + l15;
            #pragma unroll
            for (int rg = 0; rg < 4; ++rg)
                C[(size_t)(grow + rg) * N + gcol] = acc[i][j][rg];
        }
    }
}

// ---------------------------------------------------------------------------
// MFMA flash attention, two-pass. Swapped-operand QK^T, in-register P->PV,
// double-buffered swizzled global_load_lds staging, balanced 1D grid
// (verified r3).
// ---------------------------------------------------------------------------
__global__ __launch_bounds__(256, 4) void attn_mfma(
    const unsigned short* __restrict__ qk_bf,   // [2048][2560]
    const unsigned short* __restrict__ v_t,     // [1024][1024]
    const float* __restrict__ bias_diag,
    const float* __restrict__ soff,
    unsigned short* __restrict__ AO)            // [2048][2048] bf16
{
    static const unsigned char qtab[16] =
        {15, 14, 13, 12, 10, 11, 8, 9, 4, 5, 6, 7, 1, 0, 3, 2};
    const int id = (int)blockIdx.x;
    const int qt = qtab[(id >> 6) & 15];
    const int h  = id & 31;
    const int b  = (id >> 5) & 1;
    const int kh = h >> 2;
    const int tid  = threadIdx.x;
    const int lane = tid & 63;
    const int wave = tid >> 6;
    const int quad = lane >> 4;
    const int l15  = lane & 15;
    const int q0   = qt * 64;

    __shared__ short Ks[2][4096];   // [64 rows][64 cols] bf16, chunk-swizzled
    __shared__ short Vs[2][4096];   // [64 d][64 k] bf16, chunk-swizzled
    __shared__ float bd_s[1024];

    for (int i = tid; i < 1024; i += 256) bd_s[i] = bias_diag[h * 1024 + i];

    const unsigned short* Qg = qk_bf + (size_t)(b * SS + q0 + wave * 16) * QKW + h * 64;
    const unsigned short* Kg = qk_bf + (size_t)(b * SS) * QKW + 2048 + kh * 64;
    const unsigned short* Vg = v_t + (size_t)(b * 512 + kh * 64) * SS;

    const int qrow = q0 + wave * 16 + l15;      // this lane's q (S^T column)

    // Q fragments (B operand), hoisted for the whole kernel
    bf16x8 qf0 = *(const bf16x8*)(Qg + (size_t)l15 * QKW + quad * 8);
    bf16x8 qf1 = *(const bf16x8*)(Qg + (size_t)l15 * QKW + 32 + quad * 8);

// stage one 64x64 bf16 tile (512 x 16B chunks, 2/thread) with source-side
// XOR swizzle: LDS chunk (row, c') holds global chunk (row, c'^(row&7))
#define STAGE_K(j, buf) do {                                                  \
    _Pragma("unroll")                                                         \
    for (int p = 0; p < 2; ++p) {                                             \
        int ci = tid + p * 256;                                               \
        int row_ = ci >> 3;                                                   \
        int sc_  = (ci & 7) ^ (row_ & 7);                                     \
        g2l16(Kg + (size_t)((j) * 64 + row_) * QKW + sc_ * 8,                 \
              (unsigned short*)&Ks[buf][ci * 8]);                             \
    } } while (0)

#define STAGE_V(j, buf) do {                                                  \
    _Pragma("unroll")                                                         \
    for (int p = 0; p < 2; ++p) {                                             \
        int ci = tid + p * 256;                                               \
        int row_ = ci >> 3;                                                   \
        int sc_  = (ci & 7) ^ (row_ & 7);                                     \
        g2l16(Vg + (size_t)row_ * SS + (j) * 64 + sc_ * 8,                    \
              (unsigned short*)&Vs[buf][ci * 8]);                             \
    } } while (0)

    // ---------------- pass 1: l ----------------
    float lpa[4] = {0.f, 0.f, 0.f, 0.f};
    STAGE_K(0, 0);
    __syncthreads();
    int cur = 0;
    for (int j = 0; j <= qt; ++j) {
        if (j < qt) STAGE_K(j + 1, cur ^ 1);
        const short* Kb = Ks[cur];
        const bool diag = (j == qt);

        f32x4 acc[4] = {};
        #pragma unroll
        for (int nb = 0; nb < 4; ++nb) {
            if (diag && nb > wave) continue;
            int row = nb * 16 + l15, sw = row & 7;
            bf16x8 a0 = *(const bf16x8*)(Kb + row * 64 + ((quad ^ sw) * 8));
            bf16x8 a1 = *(const bf16x8*)(Kb + row * 64 + (((quad + 4) ^ sw) * 8));
            acc[nb] = __builtin_amdgcn_mfma_f32_16x16x32_bf16(a0, qf0, acc[nb], 0, 0, 0);
            acc[nb] = __builtin_amdgcn_mfma_f32_16x16x32_bf16(a1, qf1, acc[nb], 0, 0, 0);
        }
        if (!diag) {
            #pragma unroll
            for (int nb = 0; nb < 4; ++nb) {
                int rel0 = qrow - (j * 64 + nb * 16 + quad * 4);
                #pragma unroll
                for (int r = 0; r < 4; ++r)
                    lpa[r] += __expf(acc[nb][r] + bd_s[rel0 - r]);
            }
        } else {
            #pragma unroll
            for (int nb = 0; nb < 4; ++nb) {
                if (nb > wave) continue;
                #pragma unroll
                for (int r = 0; r < 4; ++r) {
                    int rel = qrow - (j * 64 + nb * 16 + quad * 4 + r);
                    if (rel >= 0) lpa[r] += __expf(acc[nb][r] + bd_s[rel]);
                }
            }
        }
        __syncthreads();
        cur ^= 1;
    }

    float lp = (lpa[0] + lpa[1]) + (lpa[2] + lpa[3]);
    lp += __shfl_xor(lp, 16, 64);
    lp += __shfl_xor(lp, 32, 64);
    const float invl = 1.f / lp;
    const float cl   = fabsf(soff[h] + 1.f) / (float)(qrow + 1) * lp;

    // ---------------- pass 2: output ----------------
    f32x4 oacc[4] = {};
    STAGE_K(0, 0);
    STAGE_V(0, 0);
    __syncthreads();
    cur = 0;
    for (int j = 0; j <= qt; ++j) {
        if (j < qt) { STAGE_K(j + 1, cur ^ 1); STAGE_V(j + 1, cur ^ 1); }
        const short* Kb = Ks[cur];
        const short* Vb = Vs[cur];
        const bool diag = (j == qt);

        f32x4 acc[4] = {};
        #pragma unroll
        for (int nb = 0; nb < 4; ++nb) {
            if (diag && nb > wave) continue;
            int row = nb * 16 + l15, sw = row & 7;
            bf16x8 a0 = *(const bf16x8*)(Kb + row * 64 + ((quad ^ sw) * 8));
            bf16x8 a1 = *(const bf16x8*)(Kb + row * 64 + (((quad + 4) ^ sw) * 8));
            acc[nb] = __builtin_amdgcn_mfma_f32_16x16x32_bf16(a0, qf0, acc[nb], 0, 0, 0);
            acc[nb] = __builtin_amdgcn_mfma_f32_16x16x32_bf16(a1, qf1, acc[nb], 0, 0, 0);
        }

        // w = relu(exp(s + bias) - cl) for this lane's q=l15, kpos quad*4+r
        unsigned int pk[4][2];
        #pragma unroll
        for (int nb = 0; nb < 4; ++nb) {
            float w[4];
            #pragma unroll
            for (int r = 0; r < 4; ++r) {
                int rel = qrow - (j * 64 + nb * 16 + quad * 4 + r);
                float e = 0.f;
                if (rel >= 0)
                    e = fmaxf(__expf(acc[nb][r] + bd_s[rel]) - cl, 0.f);
                w[r] = e;
            }
            asm("v_cvt_pk_bf16_f32 %0, %1, %2" : "=v"(pk[nb][0]) : "v"(w[0]), "v"(w[1]));
            asm("v_cvt_pk_bf16_f32 %0, %1, %2" : "=v"(pk[nb][1]) : "v"(w[2]), "v"(w[3]));
        }
        unsigned int ppk[4][2];
        #pragma unroll
        for (int nb = 0; nb < 4; ++nb) {
            ppk[nb][0] = __shfl_xor(pk[nb][0], 16, 64);
            ppk[nb][1] = __shfl_xor(pk[nb][1], 16, 64);
        }

        // PV with permuted k-slots: slot quad*8+e <-> kpos 16*(2s+(quad&1)) +
        // 8*(quad>>1) + e; V read at the same permuted (swizzled) chunk.
        const bool oddq = quad & 1;
        const int  cv   = ((quad & 1) << 1) | (quad >> 1);   // 0,2,1,3
        #pragma unroll
        for (int s = 0; s < 2; ++s) {
            if (diag && s == 1 && wave < 2) continue;   // dead kpos block
            unsigned int w0 = oddq ? ppk[2 * s + 1][0] : pk[2 * s][0];
            unsigned int w1 = oddq ? ppk[2 * s + 1][1] : pk[2 * s][1];
            unsigned int w2 = oddq ? pk[2 * s + 1][0]  : ppk[2 * s][0];
            unsigned int w3 = oddq ? pk[2 * s + 1][1]  : ppk[2 * s][1];
            u32x4 t; t[0] = w0; t[1] = w1; t[2] = w2; t[3] = w3;
            bf16x8 pf = __builtin_bit_cast(bf16x8, t);
            #pragma unroll
            for (int nd = 0; nd < 4; ++nd) {
                int rowv = nd * 16 + l15, swv = rowv & 7;
                bf16x8 vf = *(const bf16x8*)(Vb + rowv * 64 + (((cv + 4 * s) ^ swv) * 8));
                oacc[nd] = __builtin_amdgcn_mfma_f32_16x16x32_bf16(pf, vf, oacc[nd], 0, 0, 0);
            }
        }
        __syncthreads();
        cur ^= 1;
    }

    // invl for this lane's OUTPUT rows (q-sub = quad*4+r)
    float invl_r[4];
    #pragma unroll
    for (int r = 0; r < 4; ++r)
        invl_r[r] = __shfl(invl, quad * 4 + r, 64);

    unsigned short* aop = AO + (size_t)(b * SS + q0 + wave * 16 + quad * 4) * 2048
                             + h * 64 + l15;
    #pragma unroll
    for (int nd = 0; nd < 4; ++nd)
        #pragma unroll
        for (int r = 0; r < 4; ++r)
            aop[(size_t)r * 2048 + nd * 16] = f2bf(oacc[nd][r] * invl_r[r]);
#undef STAGE_K
#undef STAGE_V
}

// ---------------------------------------------------------------------------
extern "C" void kernel_launch(void* const* d_in, const int* in_sizes, int n_in,
                              void* d_out, int out_size, void* d_ws, size_t ws_size,
                              hipStream_t stream)
{
    const float* hidden    = (const float*)d_in[0];
    const float* Wq        = (const float*)d_in[2];
    const float* Wk        = (const float*)d_in[3];
    const float* Wv        = (const float*)d_in[4];
    const float* Wo        = (const float*)d_in[5];
    const float* bias_diag = (const float*)d_in[6];
    const float* soff      = (const float*)d_in[7];
    float* out = (float*)d_out;

    // Workspace aliasing:
    //  A [0,20.97M): hidden_bf(8.39) + WqkvT(12.58) -- inputs of QKV gemm.
    //                AO_bf at [12.58M..) only AFTER WqkvT is dead (attention
    //                writes AO_bf after the QKV gemm consumed WqkvT).
    //  B [20.97M,29.36M): WoT
    //  C [29.36M,41.94M): qk_bf(10.49M) + v_t(2.10M)
    char* wsb = (char*)d_ws;
    unsigned short* hidden_bf = (unsigned short*)wsb;
    unsigned short* WqkvT     = (unsigned short*)(wsb + (size_t)8388608);
    unsigned short* AO_bf     = (unsigned short*)(wsb + (size_t)12582912);
    unsigned short* WoT       = (unsigned short*)(wsb + (size_t)20971520);
    unsigned short* qk_bf     = (unsigned short*)(wsb + (size_t)29360128);
    unsigned short* v_t       = (unsigned short*)(wsb + (size_t)29360128 + (size_t)2048 * 2560 * 2);

    // 1. weight transposes + hidden convert (one launch, vectorized)
    prep<<<dim3(32, 32, 5), dim3(256), 0, stream>>>(
        hidden, Wq, Wk, Wv, Wo, hidden_bf, WqkvT, WoT);

    // 2. fused QKV projection + rope/V-transpose epilogue (384 blocks)
    gemm_qkv_fused<<<dim3(24, 16), dim3(256), 0, stream>>>(
        hidden_bf, WqkvT, qk_bf, v_t);

    // 3. two-pass LDS-staged MFMA attention, balanced 1D grid
    attn_mfma<<<dim3(1024), dim3(256), 0, stream>>>(
        qk_bf, v_t, bias_diag, soff, AO_bf);

    // 4. output projection (512 blocks, 2/CU)
    gemm_bf16_bt<<<dim3(2048 / 64, 2048 / 128), dim3(256), 0, stream>>>(
        AO_bf, WoT, out, 2048, 2048, 2048);
}

// Round 5
// 226.119 us; speedup vs baseline: 1.6460x; 1.0173x over previous
//
#include <hip/hip_runtime.h>
#include <cstdint>
#include <cstddef>

// Problem constants
#define BB   2
#define SS   1024
#define HID  2048
#define HH   32
#define KVHH 8
#define DD   64
#define NQKV 3072   // fused QKV projection width: 2048 q + 512 k + 512 v
#define QKW  2560   // qk_bf row width: 2048 q + 512 k

typedef __attribute__((ext_vector_type(8))) short bf16x8;
typedef __attribute__((ext_vector_type(4))) float f32x4;
typedef __attribute__((ext_vector_type(4))) unsigned int u32x4;

__device__ __forceinline__ unsigned short f2bf(float f) {
    unsigned int u = __float_as_uint(f);
    unsigned int r = (u + 0x7fffu + ((u >> 16) & 1u)) >> 16;
    return (unsigned short)r;
}

// async global->LDS 16B (wave-uniform LDS base + lane*16 layout required)
__device__ __forceinline__ void g2l16(const unsigned short* g, unsigned short* l) {
    __builtin_amdgcn_global_load_lds(
        (__attribute__((address_space(1))) void*)(unsigned short*)g,
        (__attribute__((address_space(3))) void*)l,
        16, 0, 0);
}

// ---------------------------------------------------------------------------
// prep (vectorized): z=0..3 weight transpose+convert (64x64 tiles, float4
// reads, ushort4 writes); z=4 hidden fp32->bf16 straight convert.
// ---------------------------------------------------------------------------
__global__ __launch_bounds__(256) void prep(
    const float* __restrict__ hidden,
    const float* __restrict__ Wq, const float* __restrict__ Wk,
    const float* __restrict__ Wv, const float* __restrict__ Wo,
    unsigned short* __restrict__ hidden_bf,
    unsigned short* __restrict__ WqkvT,
    unsigned short* __restrict__ WoT)
{
    const int z   = blockIdx.z;
    const int tid = threadIdx.x;

    if (z == 4) {   // hidden convert, 2048x2048, 64x64 tile
        int r0 = blockIdx.y * 64, c0 = blockIdx.x * 64;
        #pragma unroll
        for (int p = 0; p < 4; ++p) {
            int f = tid + p * 256;            // 0..1023
            int row = r0 + (f >> 4), c4 = c0 + (f & 15) * 4;
            float4 v = *(const float4*)&hidden[(size_t)row * 2048 + c4];
            ushort4 o;
            o.x = f2bf(v.x); o.y = f2bf(v.y); o.z = f2bf(v.z); o.w = f2bf(v.w);
            *(ushort4*)&hidden_bf[(size_t)row * 2048 + c4] = o;
        }
        return;
    }

    const float* W;
    unsigned short* Wt;
    int N;
    if (z == 0)      { W = Wq; Wt = WqkvT;                        N = 2048; }
    else if (z == 1) { W = Wk; Wt = WqkvT + (size_t)2048 * 2048;  N = 512;  }
    else if (z == 2) { W = Wv; Wt = WqkvT + (size_t)2560 * 2048;  N = 512;  }
    else             { W = Wo; Wt = WoT;                          N = 2048; }
    if (blockIdx.x * 64 >= N) return;

    // 64x64 transpose tile via LDS, stride 68 (2-way bank alias only)
    __shared__ float t[64][68];
    const int n0 = blockIdx.x * 64, k0 = blockIdx.y * 64;
    #pragma unroll
    for (int p = 0; p < 4; ++p) {
        int f = tid + p * 256;
        int row = f >> 4, c4 = (f & 15) * 4;     // row=k_local, c4=n_local
        float4 v = *(const float4*)&W[(size_t)(k0 + row) * N + n0 + c4];
        t[row][c4 + 0] = v.x; t[row][c4 + 1] = v.y;
        t[row][c4 + 2] = v.z; t[row][c4 + 3] = v.w;
    }
    __syncthreads();
    #pragma unroll
    for (int p = 0; p < 4; ++p) {
        int f = tid + p * 256;
        int nrow = f >> 4, kc4 = (f & 15) * 4;   // output row=n, col=k
        ushort4 o;
        o.x = f2bf(t[kc4 + 0][nrow]);
        o.y = f2bf(t[kc4 + 1][nrow]);
        o.z = f2bf(t[kc4 + 2][nrow]);
        o.w = f2bf(t[kc4 + 3][nrow]);
        *(ushort4*)&Wt[(size_t)(n0 + nrow) * 2048 + k0 + kc4] = o;
    }
}

// ---------------------------------------------------------------------------
// Fused QKV GEMM + rope/V-transpose epilogue. Tile 128(M) x 128(N), BK=64,
// swizzled global_load_lds staging (chunk^row&7 -> 2-way-free ds_read_b128).
// ---------------------------------------------------------------------------
__global__ __launch_bounds__(256) void gemm_qkv_fused(
    const unsigned short* __restrict__ A,     // hidden_bf [2048][2048]
    const unsigned short* __restrict__ Bt,    // WqkvT [3072][2048]
    unsigned short* __restrict__ qk_bf,       // [2048][2560]
    unsigned short* __restrict__ v_t)         // [1024][1024]
{
    __shared__ __align__(16) char smem[33024];
    short* Asb = (short*)smem;                 // [128][64] swizzled, 16 KB
    short* Bsb = (short*)(smem + 16384);       // [128][64] swizzled, 16 KB
    float* Ctf = (float*)smem;                 // [64][129] epilogue, 33 KB

    const int tid  = threadIdx.x;
    const int lane = tid & 63;
    const int wave = tid >> 6;
    const int quad = lane >> 4;
    const int l15  = lane & 15;
    const int wm = (wave >> 1) * 64, wn = (wave & 1) * 64;
    const int m0 = blockIdx.y * 128, n0 = blockIdx.x * 128;
    const int K = 2048;

    f32x4 acc[4][4] = {};

    for (int k0 = 0; k0 < K; k0 += 64) {
        #pragma unroll
        for (int p = 0; p < 4; ++p) {   // A: 1024 x 16B chunks
            int ci = tid + p * 256;
            int row = ci >> 3, sc = (ci & 7) ^ (row & 7);
            g2l16(&A[(size_t)(m0 + row) * K + k0 + sc * 8],
                  (unsigned short*)Asb + ci * 8);
        }
        #pragma unroll
        for (int p = 0; p < 4; ++p) {   // B: 1024 x 16B chunks
            int ci = tid + p * 256;
            int row = ci >> 3, sc = (ci & 7) ^ (row & 7);
            g2l16(&Bt[(size_t)(n0 + row) * K + k0 + sc * 8],
                  (unsigned short*)Bsb + ci * 8);
        }
        __syncthreads();

        #pragma unroll
        for (int s = 0; s < 2; ++s) {
            bf16x8 af[4], bfr[4];
            #pragma unroll
            for (int i = 0; i < 4; ++i) {
                int row = wm + i * 16 + l15;
                af[i] = *(const bf16x8*)(Asb + row * 64 +
                        ((((s << 2) | quad) ^ (row & 7)) * 8));
            }
            #pragma unroll
            for (int j = 0; j < 4; ++j) {
                int row = wn + j * 16 + l15;
                bfr[j] = *(const bf16x8*)(Bsb + row * 64 +
                        ((((s << 2) | quad) ^ (row & 7)) * 8));
            }
            #pragma unroll
            for (int i = 0; i < 4; ++i)
                #pragma unroll
                for (int j = 0; j < 4; ++j)
                    acc[i][j] = __builtin_amdgcn_mfma_f32_16x16x32_bf16(
                        af[i], bfr[j], acc[i][j], 0, 0, 0);
        }
        __syncthreads();
    }

    // ---- epilogue: two 64-row passes through Ct[64][129] ----
    const int bx = blockIdx.x;
    const int b  = m0 >> 10;           // batch (tile never straddles)
    const int s0 = m0 & 1023;
    const int hcg = bx * 128;          // global qk_bf col base (q/k regions)

    #pragma unroll 1
    for (int ph = 0; ph < 2; ++ph) {
        if (ph) __syncthreads();
        if ((wave >> 1) == ph) {       // waves owning rows ph*64..+63 write
            #pragma unroll
            for (int i = 0; i < 4; ++i)
                #pragma unroll
                for (int j = 0; j < 4; ++j)
                    #pragma unroll
                    for (int rg = 0; rg < 4; ++rg)
                        Ctf[(i * 16 + quad * 4 + rg) * 129 + wn + j * 16 + l15]
                            = acc[i][j][rg];
        }
        __syncthreads();

        if (bx < 20) {
            // rope q/k (two heads per tile): cols hcg + hi*64 + t
            const float scale = (bx < 16) ? 0.125f : 1.0f;
            #pragma unroll
            for (int p = 0; p < 4; ++p) {
                int idx = tid + p * 256;       // 64 rows x 2 heads x 8 tgrps
                int row = idx >> 4, hi = (idx >> 3) & 1, t0 = (idx & 7) * 4;
                int s = s0 + ph * 64 + row;
                ushort4 o1, o2;
                #pragma unroll
                for (int k = 0; k < 4; ++k) {
                    int t = t0 + k;
                    float x1 = Ctf[row * 129 + hi * 64 + t];
                    float x2 = Ctf[row * 129 + hi * 64 + t + 32];
                    float inv = __expf(-(float)t * 0.28782313662425572f);
                    float ang = (float)s * inv;
                    float c  = __cosf(ang);
                    float sn = __sinf(ang);
                    ((unsigned short*)&o1)[k] = f2bf((x1 * c - x2 * sn) * scale);
                    ((unsigned short*)&o2)[k] = f2bf((x2 * c + x1 * sn) * scale);
                }
                unsigned short* dst =
                    qk_bf + (size_t)(m0 + ph * 64 + row) * QKW + hcg + hi * 64;
                *(ushort4*)&dst[t0]      = o1;
                *(ushort4*)&dst[t0 + 32] = o2;
            }
        } else {
            // v transpose: v_t[(b*512 + (bx-20)*128 + cc)][s0 + ph*64 + srow]
            const int vb = b * 512 + (bx - 20) * 128;
            #pragma unroll
            for (int p = 0; p < 8; ++p) {
                int idx = tid + p * 256;       // 128 cc x 16 s-groups
                int cc = idx >> 4, srow = (idx & 15) * 4;
                ushort4 o;
                #pragma unroll
                for (int k = 0; k < 4; ++k)
                    ((unsigned short*)&o)[k] = f2bf(Ctf[(srow + k) * 129 + cc]);
                *(ushort4*)&v_t[(size_t)(vb + cc) * 1024 + s0 + ph * 64 + srow] = o;
            }
        }
    }
}

// ---------------------------------------------------------------------------
// bf16 MFMA GEMM, B-transposed (Wo projection). Tile 128x64, BK=64,
// swizzled staging (same 2-way-free pattern). 512 blocks = 2/CU.
// ---------------------------------------------------------------------------
__global__ __launch_bounds__(256) void gemm_bf16_bt(
    const unsigned short* __restrict__ A,
    const unsigned short* __restrict__ Bt,
    float* __restrict__ C, int M, int N, int K)
{
    __shared__ short Asb[128 * 64];   // 16 KB swizzled
    __shared__ short Bsb[64 * 64];    // 8 KB swizzled

    const int tid  = threadIdx.x;
    const int lane = tid & 63;
    const int wave = tid >> 6;
    const int quad = lane >> 4;
    const int l15  = lane & 15;
    const int wm = (wave >> 1) * 64, wn = (wave & 1) * 32;
    const int m0 = blockIdx.y * 128, n0 = blockIdx.x * 64;

    f32x4 acc[4][2] = {};

    for (int k0 = 0; k0 < K; k0 += 64) {
        #pragma unroll
        for (int p = 0; p < 4; ++p) {   // A: 1024 x 16B chunks
            int ci = tid + p * 256;
            int row = ci >> 3, sc = (ci & 7) ^ (row & 7);
            g2l16(&A[(size_t)(m0 + row) * K + k0 + sc * 8],
                  (unsigned short*)Asb + ci * 8);
        }
        #pragma unroll
        for (int p = 0; p < 2; ++p) {   // B: 512 x 16B chunks
            int ci = tid + p * 256;
            int row = ci >> 3, sc = (ci & 7) ^ (row & 7);
            g2l16(&Bt[(size_t)(n0 + row) * K + k0 + sc * 8],
                  (unsigned short*)Bsb + ci * 8);
        }
        __syncthreads();

        #pragma unroll
        for (int s = 0; s < 2; ++s) {
            bf16x8 af[4], bfr[2];
            #pragma unroll
            for (int i = 0; i < 4; ++i) {
                int row = wm + i * 16 + l15;
                af[i] = *(const bf16x8*)(Asb + row * 64 +
                        ((((s << 2) | quad) ^ (row & 7)) * 8));
            }
            #pragma unroll
            for (int j = 0; j < 2; ++j) {
                int row = wn + j * 16 + l15;
                bfr[j] = *(const bf16x8*)(Bsb + row * 64 +
                        ((((s << 2) | quad) ^ (row & 7)) * 8));
            }
            #pragma unroll
            for (int i = 0; i < 4; ++i)
                #pragma unroll
                for (int j = 0; j < 2; ++j)
                    acc[i][j] = __builtin_amdgcn_mfma_f32_16x16x32_bf16(
                        af[i], bfr[j], acc[i][j], 0, 0, 0);
        }
        __syncthreads();
    }

    #pragma unroll
    for (int i = 0; i < 4; ++i) {
        int grow = m0 + wm + i * 16 + quad * 4;
        #pragma unroll
        for (int j = 0; j < 2; ++j) {
            int gcol = n0 + wn + j * 16 + l15;
            #pragma unroll
            for (int rg = 0; rg < 4; ++rg)
                C[(size_t)(grow + rg) * N + gcol] = acc[i][j][rg];
        }
    }
}

// ---------------------------------------------------------------------------
// MFMA flash attention, two-pass, uniform-duration blocks (r5).
// 512 blocks x 512 threads. Block pi owns the complementary q-tile pair
// {15-pi, pi} (17 tile-units each -> all blocks equal). Two 4-wave groups
// split each tile's j-range (group g: j = g, g+2, ...) with group-private
// double-buffered swizzled K/V staging. Cross-group combine: lp via
// red[2][64]; oacc via one 16KB LDS pass (aliases group1's dead K staging).
// Verified math (swapped QK^T, in-reg P->PV permute, chunk^row&7 swizzle)
// unchanged from r2-r4, with wave -> w4 (wave-in-group).
// LDS: K 32K + V 32K + bd 4K + red 0.5K = 70.2 KB -> 2 blocks/CU sustained.
// ---------------------------------------------------------------------------
__global__ __launch_bounds__(512, 4) void attn_mfma(
    const unsigned short* __restrict__ qk_bf,   // [2048][2560]
    const unsigned short* __restrict__ v_t,     // [1024][1024]
    const float* __restrict__ bias_diag,
    const float* __restrict__ soff,
    unsigned short* __restrict__ AO)            // [2048][2048] bf16
{
    const int id = (int)blockIdx.x;             // 512 blocks
    const int h  = id & 31;
    const int b  = (id >> 5) & 1;
    const int pi = id >> 6;                     // 0..7
    const int kh = h >> 2;
    const int tid  = threadIdx.x;
    const int lane = tid & 63;
    const int wave = tid >> 6;                  // 0..7
    const int grp  = wave >> 2;                 // j-parity group
    const int w4   = wave & 3;                  // wave-in-group (q sub-tile)
    const int gt   = tid & 255;                 // thread-in-group
    const int quad = lane >> 4;
    const int l15  = lane & 15;

    __shared__ short Ks[2][2][4096];   // [grp][buf][64r x 64c] swizzled, 32 KB
    __shared__ short Vs[2][2][4096];   // 32 KB
    __shared__ float bd_s[1024];       // 4 KB
    __shared__ float red[2][64];       // lp cross-group exchange

    for (int i = tid; i < 1024; i += 512) bd_s[i] = bias_diag[h * 1024 + i];

    const unsigned short* Kg = qk_bf + (size_t)(b * SS) * QKW + 2048 + kh * 64;
    const unsigned short* Vg = v_t + (size_t)(b * 512 + kh * 64) * SS;

    short* KsG = &Ks[grp][0][0];
    short* VsG = &Vs[grp][0][0];
    float* Fred = (float*)&Ks[1][0][0];   // 4096 floats, aliases grp1 K staging

// stage one 64x64 bf16 tile (512 x 16B chunks, 2/group-thread), source-side
// XOR swizzle: LDS chunk (row, c') holds global chunk (row, c'^(row&7))
#define STAGE_K(j, buf) do {                                                  \
    _Pragma("unroll")                                                         \
    for (int p = 0; p < 2; ++p) {                                             \
        int ci = gt + p * 256;                                                \
        int row_ = ci >> 3;                                                   \
        int sc_  = (ci & 7) ^ (row_ & 7);                                     \
        g2l16(Kg + (size_t)((j) * 64 + row_) * QKW + sc_ * 8,                 \
              (unsigned short*)(KsG + (buf) * 4096 + ci * 8));                \
    } } while (0)

#define STAGE_V(j, buf) do {                                                  \
    _Pragma("unroll")                                                         \
    for (int p = 0; p < 2; ++p) {                                             \
        int ci = gt + p * 256;                                                \
        int row_ = ci >> 3;                                                   \
        int sc_  = (ci & 7) ^ (row_ & 7);                                     \
        g2l16(Vg + (size_t)row_ * SS + (j) * 64 + sc_ * 8,                    \
              (unsigned short*)(VsG + (buf) * 4096 + ci * 8));                \
    } } while (0)

    #pragma unroll 1
    for (int half = 0; half < 2; ++half) {
        const int qt = half ? pi : 15 - pi;
        const int q0 = qt * 64;
        const int nI = (qt + 2) >> 1;           // iterations per group
        const int qrow = q0 + w4 * 16 + l15;    // this lane's q (S^T column)

        const unsigned short* Qg =
            qk_bf + (size_t)(b * SS + q0 + w4 * 16) * QKW + h * 64;
        bf16x8 qf0 = *(const bf16x8*)(Qg + (size_t)l15 * QKW + quad * 8);
        bf16x8 qf1 = *(const bf16x8*)(Qg + (size_t)l15 * QKW + 32 + quad * 8);

        // ---------------- pass 1: l ----------------
        float lpa[4] = {0.f, 0.f, 0.f, 0.f};
        if (grp <= qt) STAGE_K(grp, 0);
        __syncthreads();                         // also covers bd_s (half 0)
        int cur = 0;
        for (int i = 0; i < nI; ++i) {
            const int j = 2 * i + grp;
            if (j + 2 <= qt) STAGE_K(j + 2, cur ^ 1);
            if (j <= qt) {
                const short* Kb = KsG + cur * 4096;
                const bool diag = (j == qt);
                f32x4 acc[4] = {};
                #pragma unroll
                for (int nb = 0; nb < 4; ++nb) {
                    if (diag && nb > w4) continue;
                    int row = nb * 16 + l15, sw = row & 7;
                    bf16x8 a0 = *(const bf16x8*)(Kb + row * 64 + ((quad ^ sw) * 8));
                    bf16x8 a1 = *(const bf16x8*)(Kb + row * 64 + (((quad + 4) ^ sw) * 8));
                    acc[nb] = __builtin_amdgcn_mfma_f32_16x16x32_bf16(a0, qf0, acc[nb], 0, 0, 0);
                    acc[nb] = __builtin_amdgcn_mfma_f32_16x16x32_bf16(a1, qf1, acc[nb], 0, 0, 0);
                }
                if (!diag) {
                    #pragma unroll
                    for (int nb = 0; nb < 4; ++nb) {
                        int rel0 = qrow - (j * 64 + nb * 16 + quad * 4);
                        #pragma unroll
                        for (int r = 0; r < 4; ++r)
                            lpa[r] += __expf(acc[nb][r] + bd_s[rel0 - r]);
                    }
                } else {
                    #pragma unroll
                    for (int nb = 0; nb < 4; ++nb) {
                        if (nb > w4) continue;
                        #pragma unroll
                        for (int r = 0; r < 4; ++r) {
                            int rel = qrow - (j * 64 + nb * 16 + quad * 4 + r);
                            if (rel >= 0) lpa[r] += __expf(acc[nb][r] + bd_s[rel]);
                        }
                    }
                }
            }
            __syncthreads();
            cur ^= 1;
        }

        // lp: quad-reduce within wave, then cross-group via LDS
        float lp = (lpa[0] + lpa[1]) + (lpa[2] + lpa[3]);
        lp += __shfl_xor(lp, 16, 64);
        lp += __shfl_xor(lp, 32, 64);
        if (quad == 0) red[grp][w4 * 16 + l15] = lp;
        __syncthreads();
        lp = red[0][w4 * 16 + l15] + red[1][w4 * 16 + l15];
        const float invl = 1.f / lp;
        const float cl   = fabsf(soff[h] + 1.f) / (float)(qrow + 1) * lp;

        // ---------------- pass 2: output ----------------
        f32x4 oacc[4] = {};
        if (grp <= qt) { STAGE_K(grp, 0); STAGE_V(grp, 0); }
        __syncthreads();
        cur = 0;
        for (int i = 0; i < nI; ++i) {
            const int j = 2 * i + grp;
            if (j + 2 <= qt) { STAGE_K(j + 2, cur ^ 1); STAGE_V(j + 2, cur ^ 1); }
            if (j <= qt) {
                const short* Kb = KsG + cur * 4096;
                const short* Vb = VsG + cur * 4096;
                const bool diag = (j == qt);

                f32x4 acc[4] = {};
                #pragma unroll
                for (int nb = 0; nb < 4; ++nb) {
                    if (diag && nb > w4) continue;
                    int row = nb * 16 + l15, sw = row & 7;
                    bf16x8 a0 = *(const bf16x8*)(Kb + row * 64 + ((quad ^ sw) * 8));
                    bf16x8 a1 = *(const bf16x8*)(Kb + row * 64 + (((quad + 4) ^ sw) * 8));
                    acc[nb] = __builtin_amdgcn_mfma_f32_16x16x32_bf16(a0, qf0, acc[nb], 0, 0, 0);
                    acc[nb] = __builtin_amdgcn_mfma_f32_16x16x32_bf16(a1, qf1, acc[nb], 0, 0, 0);
                }

                // w = relu(exp(s + bias) - cl); full tiles are mask-free
                unsigned int pk[4][2];
                if (!diag) {
                    #pragma unroll
                    for (int nb = 0; nb < 4; ++nb) {
                        float w[4];
                        int rel0 = qrow - (j * 64 + nb * 16 + quad * 4);
                        #pragma unroll
                        for (int r = 0; r < 4; ++r)
                            w[r] = fmaxf(__expf(acc[nb][r] + bd_s[rel0 - r]) - cl, 0.f);
                        asm("v_cvt_pk_bf16_f32 %0, %1, %2" : "=v"(pk[nb][0]) : "v"(w[0]), "v"(w[1]));
                        asm("v_cvt_pk_bf16_f32 %0, %1, %2" : "=v"(pk[nb][1]) : "v"(w[2]), "v"(w[3]));
                    }
                } else {
                    #pragma unroll
                    for (int nb = 0; nb < 4; ++nb) {
                        float w[4];
                        #pragma unroll
                        for (int r = 0; r < 4; ++r) {
                            int rel = qrow - (j * 64 + nb * 16 + quad * 4 + r);
                            float e = 0.f;
                            if (rel >= 0)
                                e = fmaxf(__expf(acc[nb][r] + bd_s[rel]) - cl, 0.f);
                            w[r] = e;
                        }
                        asm("v_cvt_pk_bf16_f32 %0, %1, %2" : "=v"(pk[nb][0]) : "v"(w[0]), "v"(w[1]));
                        asm("v_cvt_pk_bf16_f32 %0, %1, %2" : "=v"(pk[nb][1]) : "v"(w[2]), "v"(w[3]));
                    }
                }
                unsigned int ppk[4][2];
                #pragma unroll
                for (int nb = 0; nb < 4; ++nb) {
                    ppk[nb][0] = __shfl_xor(pk[nb][0], 16, 64);
                    ppk[nb][1] = __shfl_xor(pk[nb][1], 16, 64);
                }

                // PV with permuted k-slots (bijection per 64-tile; sums over k)
                const bool oddq = quad & 1;
                const int  cv   = ((quad & 1) << 1) | (quad >> 1);   // 0,2,1,3
                #pragma unroll
                for (int s = 0; s < 2; ++s) {
                    if (diag && s == 1 && w4 < 2) continue;   // dead kpos block
                    unsigned int w0 = oddq ? ppk[2 * s + 1][0] : pk[2 * s][0];
                    unsigned int w1 = oddq ? ppk[2 * s + 1][1] : pk[2 * s][1];
                    unsigned int w2 = oddq ? pk[2 * s + 1][0]  : ppk[2 * s][0];
                    unsigned int w3 = oddq ? pk[2 * s + 1][1]  : ppk[2 * s][1];
                    u32x4 t; t[0] = w0; t[1] = w1; t[2] = w2; t[3] = w3;
                    bf16x8 pf = __builtin_bit_cast(bf16x8, t);
                    #pragma unroll
                    for (int nd = 0; nd < 4; ++nd) {
                        int rowv = nd * 16 + l15, swv = rowv & 7;
                        bf16x8 vf = *(const bf16x8*)(Vb + rowv * 64 + (((cv + 4 * s) ^ swv) * 8));
                        oacc[nd] = __builtin_amdgcn_mfma_f32_16x16x32_bf16(pf, vf, oacc[nd], 0, 0, 0);
                    }
                }
            }
            __syncthreads();
            cur ^= 1;
        }

        // ---- cross-group oacc reduce (grp1 -> LDS, grp0 adds) + output ----
        if (grp == 1) {
            #pragma unroll
            for (int nd = 0; nd < 4; ++nd)
                #pragma unroll
                for (int r = 0; r < 4; ++r)
                    Fred[(w4 * 16 + quad * 4 + r) * 64 + nd * 16 + l15] = oacc[nd][r];
        }
        __syncthreads();
        if (grp == 0) {
            float invl_r[4];
            #pragma unroll
            for (int r = 0; r < 4; ++r)
                invl_r[r] = __shfl(invl, quad * 4 + r, 64);
            unsigned short* aop =
                AO + (size_t)(b * SS + q0 + w4 * 16 + quad * 4) * 2048 + h * 64 + l15;
            #pragma unroll
            for (int nd = 0; nd < 4; ++nd)
                #pragma unroll
                for (int r = 0; r < 4; ++r) {
                    float o = (oacc[nd][r] +
                               Fred[(w4 * 16 + quad * 4 + r) * 64 + nd * 16 + l15])
                              * invl_r[r];
                    aop[(size_t)r * 2048 + nd * 16] = f2bf(o);
                }
        }
        __syncthreads();   // Fred/staging safe before next half's staging
    }
#undef STAGE_K
#undef STAGE_V
}

// ---------------------------------------------------------------------------
extern "C" void kernel_launch(void* const* d_in, const int* in_sizes, int n_in,
                              void* d_out, int out_size, void* d_ws, size_t ws_size,
                              hipStream_t stream)
{
    const float* hidden    = (const float*)d_in[0];
    const float* Wq        = (const float*)d_in[2];
    const float* Wk        = (const float*)d_in[3];
    const float* Wv        = (const float*)d_in[4];
    const float* Wo        = (const float*)d_in[5];
    const float* bias_diag = (const float*)d_in[6];
    const float* soff      = (const float*)d_in[7];
    float* out = (float*)d_out;

    // Workspace aliasing:
    //  A [0,20.97M): hidden_bf(8.39) + WqkvT(12.58) -- inputs of QKV gemm.
    //                AO_bf at [12.58M..) only AFTER WqkvT is dead (attention
    //                writes AO_bf after the QKV gemm consumed WqkvT).
    //  B [20.97M,29.36M): WoT
    //  C [29.36M,41.94M): qk_bf(10.49M) + v_t(2.10M)
    char* wsb = (char*)d_ws;
    unsigned short* hidden_bf = (unsigned short*)wsb;
    unsigned short* WqkvT     = (unsigned short*)(wsb + (size_t)8388608);
    unsigned short* AO_bf     = (unsigned short*)(wsb + (size_t)12582912);
    unsigned short* WoT       = (unsigned short*)(wsb + (size_t)20971520);
    unsigned short* qk_bf     = (unsigned short*)(wsb + (size_t)29360128);
    unsigned short* v_t       = (unsigned short*)(wsb + (size_t)29360128 + (size_t)2048 * 2560 * 2);

    // 1. weight transposes + hidden convert (one launch, vectorized)
    prep<<<dim3(32, 32, 5), dim3(256), 0, stream>>>(
        hidden, Wq, Wk, Wv, Wo, hidden_bf, WqkvT, WoT);

    // 2. fused QKV projection + rope/V-transpose epilogue (384 blocks)
    gemm_qkv_fused<<<dim3(24, 16), dim3(256), 0, stream>>>(
        hidden_bf, WqkvT, qk_bf, v_t);

    // 3. two-pass MFMA attention, uniform-duration 512x512 blocks
    attn_mfma<<<dim3(512), dim3(512), 0, stream>>>(
        qk_bf, v_t, bias_diag, soff, AO_bf);

    // 4. output projection (512 blocks, 2/CU)
    gemm_bf16_bt<<<dim3(2048 / 64, 2048 / 128), dim3(256), 0, stream>>>(
        AO_bf, WoT, out, 2048, 2048, 2048);
}

// Round 6
// 203.153 us; speedup vs baseline: 1.8321x; 1.1130x over previous
//
#include <hip/hip_runtime.h>
#include <cstdint>
#include <cstddef>

// Problem constants
#define BB   2
#define SS   1024
#define HID  2048
#define HH   32
#define KVHH 8
#define DD   64
#define NQKV 3072   // fused QKV projection width: 2048 q + 512 k + 512 v
#define QKW  2560   // qk_bf row width: 2048 q + 512 k

typedef __attribute__((ext_vector_type(8))) short bf16x8;
typedef __attribute__((ext_vector_type(4))) float f32x4;
typedef __attribute__((ext_vector_type(4))) unsigned int u32x4;

__device__ __forceinline__ unsigned short f2bf(float f) {
    unsigned int u = __float_as_uint(f);
    unsigned int r = (u + 0x7fffu + ((u >> 16) & 1u)) >> 16;
    return (unsigned short)r;
}

// async global->LDS 16B (wave-uniform LDS base + lane*16 layout required)
__device__ __forceinline__ void g2l16(const unsigned short* g, unsigned short* l) {
    __builtin_amdgcn_global_load_lds(
        (__attribute__((address_space(1))) void*)(unsigned short*)g,
        (__attribute__((address_space(3))) void*)l,
        16, 0, 0);
}

// ---------------------------------------------------------------------------
// prep (vectorized): z=0..3 weight transpose+convert (64x64 tiles, float4
// reads, ushort4 writes); z=4 hidden fp32->bf16 straight convert.
// ---------------------------------------------------------------------------
__global__ __launch_bounds__(256) void prep(
    const float* __restrict__ hidden,
    const float* __restrict__ Wq, const float* __restrict__ Wk,
    const float* __restrict__ Wv, const float* __restrict__ Wo,
    unsigned short* __restrict__ hidden_bf,
    unsigned short* __restrict__ WqkvT,
    unsigned short* __restrict__ WoT)
{
    const int z   = blockIdx.z;
    const int tid = threadIdx.x;

    if (z == 4) {   // hidden convert, 2048x2048, 64x64 tile
        int r0 = blockIdx.y * 64, c0 = blockIdx.x * 64;
        #pragma unroll
        for (int p = 0; p < 4; ++p) {
            int f = tid + p * 256;            // 0..1023
            int row = r0 + (f >> 4), c4 = c0 + (f & 15) * 4;
            float4 v = *(const float4*)&hidden[(size_t)row * 2048 + c4];
            ushort4 o;
            o.x = f2bf(v.x); o.y = f2bf(v.y); o.z = f2bf(v.z); o.w = f2bf(v.w);
            *(ushort4*)&hidden_bf[(size_t)row * 2048 + c4] = o;
        }
        return;
    }

    const float* W;
    unsigned short* Wt;
    int N;
    if (z == 0)      { W = Wq; Wt = WqkvT;                        N = 2048; }
    else if (z == 1) { W = Wk; Wt = WqkvT + (size_t)2048 * 2048;  N = 512;  }
    else if (z == 2) { W = Wv; Wt = WqkvT + (size_t)2560 * 2048;  N = 512;  }
    else             { W = Wo; Wt = WoT;                          N = 2048; }
    if (blockIdx.x * 64 >= N) return;

    // 64x64 transpose tile via LDS, stride 68 (2-way bank alias only)
    __shared__ float t[64][68];
    const int n0 = blockIdx.x * 64, k0 = blockIdx.y * 64;
    #pragma unroll
    for (int p = 0; p < 4; ++p) {
        int f = tid + p * 256;
        int row = f >> 4, c4 = (f & 15) * 4;     // row=k_local, c4=n_local
        float4 v = *(const float4*)&W[(size_t)(k0 + row) * N + n0 + c4];
        t[row][c4 + 0] = v.x; t[row][c4 + 1] = v.y;
        t[row][c4 + 2] = v.z; t[row][c4 + 3] = v.w;
    }
    __syncthreads();
    #pragma unroll
    for (int p = 0; p < 4; ++p) {
        int f = tid + p * 256;
        int nrow = f >> 4, kc4 = (f & 15) * 4;   // output row=n, col=k
        ushort4 o;
        o.x = f2bf(t[kc4 + 0][nrow]);
        o.y = f2bf(t[kc4 + 1][nrow]);
        o.z = f2bf(t[kc4 + 2][nrow]);
        o.w = f2bf(t[kc4 + 3][nrow]);
        *(ushort4*)&Wt[(size_t)(n0 + nrow) * 2048 + k0 + kc4] = o;
    }
}

// ---------------------------------------------------------------------------
// Fused QKV GEMM + rope/V-transpose epilogue. Tile 128(M) x 64(N), BK=64,
// 2-phase double-buffered swizzled global_load_lds staging: issue next
// K-tile's stage BEFORE ds_read+MFMA, one vmcnt(0)+barrier per K-step.
// Grid (48, 16) = 768 blocks = 3/CU uniform (LDS 48KB -> 3 blocks fit).
// bx<32 -> q head bx; 32..39 -> k head bx-32; 40..47 -> v head bx-40.
// Epilogue: Ct[128][65] fp32 aliases the staging buffers.
// ---------------------------------------------------------------------------
__global__ __launch_bounds__(256) void gemm_qkv_fused(
    const unsigned short* __restrict__ A,     // hidden_bf [2048][2048]
    const unsigned short* __restrict__ Bt,    // WqkvT [3072][2048]
    unsigned short* __restrict__ qk_bf,       // [2048][2560]
    unsigned short* __restrict__ v_t)         // [1024][1024]
{
    __shared__ __align__(16) char smem[49152];   // 2 x (A 16KB + B 8KB)
    float* Ctf = (float*)smem;                   // [128][65] epilogue alias

    const int tid  = threadIdx.x;
    const int lane = tid & 63;
    const int wave = tid >> 6;
    const int quad = lane >> 4;
    const int l15  = lane & 15;
    const int wm = (wave >> 1) * 64, wn = (wave & 1) * 32;
    const int m0 = blockIdx.y * 128, n0 = blockIdx.x * 64;
    const int K = 2048;

    f32x4 acc[4][2] = {};

// stage A (128x64, 1024 chunks, 4/thr) + B (64x64, 512 chunks, 2/thr),
// source-side XOR swizzle chunk' = chunk ^ (row&7)
#define STAGE_Q(k0s, buf) do {                                                \
    unsigned short* Ad = (unsigned short*)(smem + (buf) * 24576);             \
    unsigned short* Bd = (unsigned short*)(smem + (buf) * 24576 + 16384);     \
    _Pragma("unroll")                                                         \
    for (int p = 0; p < 4; ++p) {                                             \
        int ci = tid + p * 256;                                               \
        int row_ = ci >> 3, sc_ = (ci & 7) ^ (row_ & 7);                      \
        g2l16(&A[(size_t)(m0 + row_) * K + (k0s) + sc_ * 8], Ad + ci * 8);    \
    }                                                                         \
    _Pragma("unroll")                                                         \
    for (int p = 0; p < 2; ++p) {                                             \
        int ci = tid + p * 256;                                               \
        int row_ = ci >> 3, sc_ = (ci & 7) ^ (row_ & 7);                      \
        g2l16(&Bt[(size_t)(n0 + row_) * K + (k0s) + sc_ * 8], Bd + ci * 8);   \
    } } while (0)

    STAGE_Q(0, 0);
    __syncthreads();
    int cur = 0;
    for (int k0 = 0; k0 < K; k0 += 64) {
        if (k0 + 64 < K) STAGE_Q(k0 + 64, cur ^ 1);
        const short* Ab = (const short*)(smem + cur * 24576);
        const short* Bb = (const short*)(smem + cur * 24576 + 16384);

        #pragma unroll
        for (int s = 0; s < 2; ++s) {
            bf16x8 af[4], bfr[2];
            #pragma unroll
            for (int i = 0; i < 4; ++i) {
                int row = wm + i * 16 + l15;
                af[i] = *(const bf16x8*)(Ab + row * 64 +
                        ((((s << 2) | quad) ^ (row & 7)) * 8));
            }
            #pragma unroll
            for (int j = 0; j < 2; ++j) {
                int row = wn + j * 16 + l15;
                bfr[j] = *(const bf16x8*)(Bb + row * 64 +
                        ((((s << 2) | quad) ^ (row & 7)) * 8));
            }
            #pragma unroll
            for (int i = 0; i < 4; ++i)
                #pragma unroll
                for (int j = 0; j < 2; ++j)
                    acc[i][j] = __builtin_amdgcn_mfma_f32_16x16x32_bf16(
                        af[i], bfr[j], acc[i][j], 0, 0, 0);
        }
        __syncthreads();
        cur ^= 1;
    }

    // ---- epilogue: fragments -> Ct[128][65] fp32 (aliases staging) ----
    #pragma unroll
    for (int i = 0; i < 4; ++i)
        #pragma unroll
        for (int j = 0; j < 2; ++j)
            #pragma unroll
            for (int rg = 0; rg < 4; ++rg)
                Ctf[(wm + i * 16 + quad * 4 + rg) * 65 + wn + j * 16 + l15]
                    = acc[i][j][rg];
    __syncthreads();

    const int bx = blockIdx.x;
    const int b  = m0 >> 10;           // batch (tile never straddles)
    const int s0 = m0 & 1023;

    if (bx < 40) {
        // rope q/k: qk_bf col base = bx*64 (q: 0..2047; k: 2048 + (bx-32)*64)
        const int hc = bx * 64;
        const float scale = (bx < 32) ? 0.125f : 1.0f;
        #pragma unroll
        for (int p = 0; p < 4; ++p) {
            int idx = tid + p * 256;          // 128 rows x 8 t-groups
            int row = idx >> 3, t0 = (idx & 7) * 4;
            int s = s0 + row;
            ushort4 o1, o2;
            #pragma unroll
            for (int k = 0; k < 4; ++k) {
                int t = t0 + k;
                float x1 = Ctf[row * 65 + t];
                float x2 = Ctf[row * 65 + t + 32];
                float inv = __expf(-(float)t * 0.28782313662425572f);
                float ang = (float)s * inv;
                float c  = __cosf(ang);
                float sn = __sinf(ang);
                ((unsigned short*)&o1)[k] = f2bf((x1 * c - x2 * sn) * scale);
                ((unsigned short*)&o2)[k] = f2bf((x2 * c + x1 * sn) * scale);
            }
            unsigned short* dst = qk_bf + (size_t)(m0 + row) * QKW + hc;
            *(ushort4*)&dst[t0]      = o1;
            *(ushort4*)&dst[t0 + 32] = o2;
        }
    } else {
        // v transpose: v_t[(b*512 + (bx-40)*64 + c)][s0 + srow]
        const int vb = b * 512 + (bx - 40) * 64;
        #pragma unroll
        for (int p = 0; p < 8; ++p) {
            int idx = tid + p * 256;          // 64 c x 32 s-groups
            int c = idx >> 5, srow = (idx & 31) * 4;
            ushort4 o;
            #pragma unroll
            for (int k = 0; k < 4; ++k)
                ((unsigned short*)&o)[k] = f2bf(Ctf[(srow + k) * 65 + c]);
            *(ushort4*)&v_t[(size_t)(vb + c) * 1024 + s0 + srow] = o;
        }
    }
#undef STAGE_Q
}

// ---------------------------------------------------------------------------
// bf16 MFMA GEMM, B-transposed (Wo projection). Tile 128x64, BK=64,
// 2-phase double-buffered swizzled staging. 512 blocks = 2/CU uniform.
// ---------------------------------------------------------------------------
__global__ __launch_bounds__(256) void gemm_bf16_bt(
    const unsigned short* __restrict__ A,
    const unsigned short* __restrict__ Bt,
    float* __restrict__ C, int M, int N, int K)
{
    __shared__ __align__(16) char smem[49152];   // 2 x (A 16KB + B 8KB)

    const int tid  = threadIdx.x;
    const int lane = tid & 63;
    const int wave = tid >> 6;
    const int quad = lane >> 4;
    const int l15  = lane & 15;
    const int wm = (wave >> 1) * 64, wn = (wave & 1) * 32;
    const int m0 = blockIdx.y * 128, n0 = blockIdx.x * 64;

    f32x4 acc[4][2] = {};

#define STAGE_O(k0s, buf) do {                                                \
    unsigned short* Ad = (unsigned short*)(smem + (buf) * 24576);             \
    unsigned short* Bd = (unsigned short*)(smem + (buf) * 24576 + 16384);     \
    _Pragma("unroll")                                                         \
    for (int p = 0; p < 4; ++p) {                                             \
        int ci = tid + p * 256;                                               \
        int row_ = ci >> 3, sc_ = (ci & 7) ^ (row_ & 7);                      \
        g2l16(&A[(size_t)(m0 + row_) * K + (k0s) + sc_ * 8], Ad + ci * 8);    \
    }                                                                         \
    _Pragma("unroll")                                                         \
    for (int p = 0; p < 2; ++p) {                                             \
        int ci = tid + p * 256;                                               \
        int row_ = ci >> 3, sc_ = (ci & 7) ^ (row_ & 7);                      \
        g2l16(&Bt[(size_t)(n0 + row_) * K + (k0s) + sc_ * 8], Bd + ci * 8);   \
    } } while (0)

    STAGE_O(0, 0);
    __syncthreads();
    int cur = 0;
    for (int k0 = 0; k0 < K; k0 += 64) {
        if (k0 + 64 < K) STAGE_O(k0 + 64, cur ^ 1);
        const short* Ab = (const short*)(smem + cur * 24576);
        const short* Bb = (const short*)(smem + cur * 24576 + 16384);

        #pragma unroll
        for (int s = 0; s < 2; ++s) {
            bf16x8 af[4], bfr[2];
            #pragma unroll
            for (int i = 0; i < 4; ++i) {
                int row = wm + i * 16 + l15;
                af[i] = *(const bf16x8*)(Ab + row * 64 +
                        ((((s << 2) | quad) ^ (row & 7)) * 8));
            }
            #pragma unroll
            for (int j = 0; j < 2; ++j) {
                int row = wn + j * 16 + l15;
                bfr[j] = *(const bf16x8*)(Bb + row * 64 +
                        ((((s << 2) | quad) ^ (row & 7)) * 8));
            }
            #pragma unroll
            for (int i = 0; i < 4; ++i)
                #pragma unroll
                for (int j = 0; j < 2; ++j)
                    acc[i][j] = __builtin_amdgcn_mfma_f32_16x16x32_bf16(
                        af[i], bfr[j], acc[i][j], 0, 0, 0);
        }
        __syncthreads();
        cur ^= 1;
    }

    #pragma unroll
    for (int i = 0; i < 4; ++i) {
        int grow = m0 + wm + i * 16 + quad * 4;
        #pragma unroll
        for (int j = 0; j < 2; ++j) {
            int gcol = n0 + wn + j * 16 + l15;
            #pragma unroll
            for (int rg = 0; rg < 4; ++rg)
                C[(size_t)(grow + rg) * N + gcol] = acc[i][j][rg];
        }
    }
#undef STAGE_O
}

// ---------------------------------------------------------------------------
// MFMA flash attention, two-pass, uniform-duration blocks (r5, unchanged).
// 512 blocks x 512 threads. Block pi owns the complementary q-tile pair
// {15-pi, pi}. Two 4-wave groups split each tile's j-range with
// group-private double-buffered swizzled K/V staging.
// ---------------------------------------------------------------------------
__global__ __launch_bounds__(512, 4) void attn_mfma(
    const unsigned short* __restrict__ qk_bf,   // [2048][2560]
    const unsigned short* __restrict__ v_t,     // [1024][1024]
    const float* __restrict__ bias_diag,
    const float* __restrict__ soff,
    unsigned short* __restrict__ AO)            // [2048][2048] bf16
{
    const int id = (int)blockIdx.x;             // 512 blocks
    const int h  = id & 31;
    const int b  = (id >> 5) & 1;
    const int pi = id >> 6;                     // 0..7
    const int kh = h >> 2;
    const int tid  = threadIdx.x;
    const int lane = tid & 63;
    const int wave = tid >> 6;                  // 0..7
    const int grp  = wave >> 2;                 // j-parity group
    const int w4   = wave & 3;                  // wave-in-group (q sub-tile)
    const int gt   = tid & 255;                 // thread-in-group
    const int quad = lane >> 4;
    const int l15  = lane & 15;

    __shared__ short Ks[2][2][4096];   // [grp][buf][64r x 64c] swizzled, 32 KB
    __shared__ short Vs[2][2][4096];   // 32 KB
    __shared__ float bd_s[1024];       // 4 KB
    __shared__ float red[2][64];       // lp cross-group exchange

    for (int i = tid; i < 1024; i += 512) bd_s[i] = bias_diag[h * 1024 + i];

    const unsigned short* Kg = qk_bf + (size_t)(b * SS) * QKW + 2048 + kh * 64;
    const unsigned short* Vg = v_t + (size_t)(b * 512 + kh * 64) * SS;

    short* KsG = &Ks[grp][0][0];
    short* VsG = &Vs[grp][0][0];
    float* Fred = (float*)&Ks[1][0][0];   // 4096 floats, aliases grp1 K staging

#define STAGE_K(j, buf) do {                                                  \
    _Pragma("unroll")                                                         \
    for (int p = 0; p < 2; ++p) {                                             \
        int ci = gt + p * 256;                                                \
        int row_ = ci >> 3;                                                   \
        int sc_  = (ci & 7) ^ (row_ & 7);                                     \
        g2l16(Kg + (size_t)((j) * 64 + row_) * QKW + sc_ * 8,                 \
              (unsigned short*)(KsG + (buf) * 4096 + ci * 8));                \
    } } while (0)

#define STAGE_V(j, buf) do {                                                  \
    _Pragma("unroll")                                                         \
    for (int p = 0; p < 2; ++p) {                                             \
        int ci = gt + p * 256;                                                \
        int row_ = ci >> 3;                                                   \
        int sc_  = (ci & 7) ^ (row_ & 7);                                     \
        g2l16(Vg + (size_t)row_ * SS + (j) * 64 + sc_ * 8,                    \
              (unsigned short*)(VsG + (buf) * 4096 + ci * 8));                \
    } } while (0)

    #pragma unroll 1
    for (int half = 0; half < 2; ++half) {
        const int qt = half ? pi : 15 - pi;
        const int q0 = qt * 64;
        const int nI = (qt + 2) >> 1;           // iterations per group
        const int qrow = q0 + w4 * 16 + l15;    // this lane's q (S^T column)

        const unsigned short* Qg =
            qk_bf + (size_t)(b * SS + q0 + w4 * 16) * QKW + h * 64;
        bf16x8 qf0 = *(const bf16x8*)(Qg + (size_t)l15 * QKW + quad * 8);
        bf16x8 qf1 = *(const bf16x8*)(Qg + (size_t)l15 * QKW + 32 + quad * 8);

        // ---------------- pass 1: l ----------------
        float lpa[4] = {0.f, 0.f, 0.f, 0.f};
        if (grp <= qt) STAGE_K(grp, 0);
        __syncthreads();                         // also covers bd_s (half 0)
        int cur = 0;
        for (int i = 0; i < nI; ++i) {
            const int j = 2 * i + grp;
            if (j + 2 <= qt) STAGE_K(j + 2, cur ^ 1);
            if (j <= qt) {
                const short* Kb = KsG + cur * 4096;
                const bool diag = (j == qt);
                f32x4 acc[4] = {};
                #pragma unroll
                for (int nb = 0; nb < 4; ++nb) {
                    if (diag && nb > w4) continue;
                    int row = nb * 16 + l15, sw = row & 7;
                    bf16x8 a0 = *(const bf16x8*)(Kb + row * 64 + ((quad ^ sw) * 8));
                    bf16x8 a1 = *(const bf16x8*)(Kb + row * 64 + (((quad + 4) ^ sw) * 8));
                    acc[nb] = __builtin_amdgcn_mfma_f32_16x16x32_bf16(a0, qf0, acc[nb], 0, 0, 0);
                    acc[nb] = __builtin_amdgcn_mfma_f32_16x16x32_bf16(a1, qf1, acc[nb], 0, 0, 0);
                }
                if (!diag) {
                    #pragma unroll
                    for (int nb = 0; nb < 4; ++nb) {
                        int rel0 = qrow - (j * 64 + nb * 16 + quad * 4);
                        #pragma unroll
                        for (int r = 0; r < 4; ++r)
                            lpa[r] += __expf(acc[nb][r] + bd_s[rel0 - r]);
                    }
                } else {
                    #pragma unroll
                    for (int nb = 0; nb < 4; ++nb) {
                        if (nb > w4) continue;
                        #pragma unroll
                        for (int r = 0; r < 4; ++r) {
                            int rel = qrow - (j * 64 + nb * 16 + quad * 4 + r);
                            if (rel >= 0) lpa[r] += __expf(acc[nb][r] + bd_s[rel]);
                        }
                    }
                }
            }
            __syncthreads();
            cur ^= 1;
        }

        // lp: quad-reduce within wave, then cross-group via LDS
        float lp = (lpa[0] + lpa[1]) + (lpa[2] + lpa[3]);
        lp += __shfl_xor(lp, 16, 64);
        lp += __shfl_xor(lp, 32, 64);
        if (quad == 0) red[grp][w4 * 16 + l15] = lp;
        __syncthreads();
        lp = red[0][w4 * 16 + l15] + red[1][w4 * 16 + l15];
        const float invl = 1.f / lp;
        const float cl   = fabsf(soff[h] + 1.f) / (float)(qrow + 1) * lp;

        // ---------------- pass 2: output ----------------
        f32x4 oacc[4] = {};
        if (grp <= qt) { STAGE_K(grp, 0); STAGE_V(grp, 0); }
        __syncthreads();
        cur = 0;
        for (int i = 0; i < nI; ++i) {
            const int j = 2 * i + grp;
            if (j + 2 <= qt) { STAGE_K(j + 2, cur ^ 1); STAGE_V(j + 2, cur ^ 1); }
            if (j <= qt) {
                const short* Kb = KsG + cur * 4096;
                const short* Vb = VsG + cur * 4096;
                const bool diag = (j == qt);

                f32x4 acc[4] = {};
                #pragma unroll
                for (int nb = 0; nb < 4; ++nb) {
                    if (diag && nb > w4) continue;
                    int row = nb * 16 + l15, sw = row & 7;
                    bf16x8 a0 = *(const bf16x8*)(Kb + row * 64 + ((quad ^ sw) * 8));
                    bf16x8 a1 = *(const bf16x8*)(Kb + row * 64 + (((quad + 4) ^ sw) * 8));
                    acc[nb] = __builtin_amdgcn_mfma_f32_16x16x32_bf16(a0, qf0, acc[nb], 0, 0, 0);
                    acc[nb] = __builtin_amdgcn_mfma_f32_16x16x32_bf16(a1, qf1, acc[nb], 0, 0, 0);
                }

                // w = relu(exp(s + bias) - cl); full tiles are mask-free
                unsigned int pk[4][2];
                if (!diag) {
                    #pragma unroll
                    for (int nb = 0; nb < 4; ++nb) {
                        float w[4];
                        int rel0 = qrow - (j * 64 + nb * 16 + quad * 4);
                        #pragma unroll
                        for (int r = 0; r < 4; ++r)
                            w[r] = fmaxf(__expf(acc[nb][r] + bd_s[rel0 - r]) - cl, 0.f);
                        asm("v_cvt_pk_bf16_f32 %0, %1, %2" : "=v"(pk[nb][0]) : "v"(w[0]), "v"(w[1]));
                        asm("v_cvt_pk_bf16_f32 %0, %1, %2" : "=v"(pk[nb][1]) : "v"(w[2]), "v"(w[3]));
                    }
                } else {
                    #pragma unroll
                    for (int nb = 0; nb < 4; ++nb) {
                        float w[4];
                        #pragma unroll
                        for (int r = 0; r < 4; ++r) {
                            int rel = qrow - (j * 64 + nb * 16 + quad * 4 + r);
                            float e = 0.f;
                            if (rel >= 0)
                                e = fmaxf(__expf(acc[nb][r] + bd_s[rel]) - cl, 0.f);
                            w[r] = e;
                        }
                        asm("v_cvt_pk_bf16_f32 %0, %1, %2" : "=v"(pk[nb][0]) : "v"(w[0]), "v"(w[1]));
                        asm("v_cvt_pk_bf16_f32 %0, %1, %2" : "=v"(pk[nb][1]) : "v"(w[2]), "v"(w[3]));
                    }
                }
                unsigned int ppk[4][2];
                #pragma unroll
                for (int nb = 0; nb < 4; ++nb) {
                    ppk[nb][0] = __shfl_xor(pk[nb][0], 16, 64);
                    ppk[nb][1] = __shfl_xor(pk[nb][1], 16, 64);
                }

                // PV with permuted k-slots (bijection per 64-tile; sums over k)
                const bool oddq = quad & 1;
                const int  cv   = ((quad & 1) << 1) | (quad >> 1);   // 0,2,1,3
                #pragma unroll
                for (int s = 0; s < 2; ++s) {
                    if (diag && s == 1 && w4 < 2) continue;   // dead kpos block
                    unsigned int w0 = oddq ? ppk[2 * s + 1][0] : pk[2 * s][0];
                    unsigned int w1 = oddq ? ppk[2 * s + 1][1] : pk[2 * s][1];
                    unsigned int w2 = oddq ? pk[2 * s + 1][0]  : ppk[2 * s][0];
                    unsigned int w3 = oddq ? pk[2 * s + 1][1]  : ppk[2 * s][1];
                    u32x4 t; t[0] = w0; t[1] = w1; t[2] = w2; t[3] = w3;
                    bf16x8 pf = __builtin_bit_cast(bf16x8, t);
                    #pragma unroll
                    for (int nd = 0; nd < 4; ++nd) {
                        int rowv = nd * 16 + l15, swv = rowv & 7;
                        bf16x8 vf = *(const bf16x8*)(Vb + rowv * 64 + (((cv + 4 * s) ^ swv) * 8));
                        oacc[nd] = __builtin_amdgcn_mfma_f32_16x16x32_bf16(pf, vf, oacc[nd], 0, 0, 0);
                    }
                }
            }
            __syncthreads();
            cur ^= 1;
        }

        // ---- cross-group oacc reduce (grp1 -> LDS, grp0 adds) + output ----
        if (grp == 1) {
            #pragma unroll
            for (int nd = 0; nd < 4; ++nd)
                #pragma unroll
                for (int r = 0; r < 4; ++r)
                    Fred[(w4 * 16 + quad * 4 + r) * 64 + nd * 16 + l15] = oacc[nd][r];
        }
        __syncthreads();
        if (grp == 0) {
            float invl_r[4];
            #pragma unroll
            for (int r = 0; r < 4; ++r)
                invl_r[r] = __shfl(invl, quad * 4 + r, 64);
            unsigned short* aop =
                AO + (size_t)(b * SS + q0 + w4 * 16 + quad * 4) * 2048 + h * 64 + l15;
            #pragma unroll
            for (int nd = 0; nd < 4; ++nd)
                #pragma unroll
                for (int r = 0; r < 4; ++r) {
                    float o = (oacc[nd][r] +
                               Fred[(w4 * 16 + quad * 4 + r) * 64 + nd * 16 + l15])
                              * invl_r[r];
                    aop[(size_t)r * 2048 + nd * 16] = f2bf(o);
                }
        }
        __syncthreads();   // Fred/staging safe before next half's staging
    }
#undef STAGE_K
#undef STAGE_V
}

// ---------------------------------------------------------------------------
extern "C" void kernel_launch(void* const* d_in, const int* in_sizes, int n_in,
                              void* d_out, int out_size, void* d_ws, size_t ws_size,
                              hipStream_t stream)
{
    const float* hidden    = (const float*)d_in[0];
    const float* Wq        = (const float*)d_in[2];
    const float* Wk        = (const float*)d_in[3];
    const float* Wv        = (const float*)d_in[4];
    const float* Wo        = (const float*)d_in[5];
    const float* bias_diag = (const float*)d_in[6];
    const float* soff      = (const float*)d_in[7];
    float* out = (float*)d_out;

    // Workspace aliasing:
    //  A [0,20.97M): hidden_bf(8.39) + WqkvT(12.58) -- inputs of QKV gemm.
    //                AO_bf at [12.58M..) only AFTER WqkvT is dead (attention
    //                writes AO_bf after the QKV gemm consumed WqkvT).
    //  B [20.97M,29.36M): WoT
    //  C [29.36M,41.94M): qk_bf(10.49M) + v_t(2.10M)
    char* wsb = (char*)d_ws;
    unsigned short* hidden_bf = (unsigned short*)wsb;
    unsigned short* WqkvT     = (unsigned short*)(wsb + (size_t)8388608);
    unsigned short* AO_bf     = (unsigned short*)(wsb + (size_t)12582912);
    unsigned short* WoT       = (unsigned short*)(wsb + (size_t)20971520);
    unsigned short* qk_bf     = (unsigned short*)(wsb + (size_t)29360128);
    unsigned short* v_t       = (unsigned short*)(wsb + (size_t)29360128 + (size_t)2048 * 2560 * 2);

    // 1. weight transposes + hidden convert (one launch, vectorized)
    prep<<<dim3(32, 32, 5), dim3(256), 0, stream>>>(
        hidden, Wq, Wk, Wv, Wo, hidden_bf, WqkvT, WoT);

    // 2. fused QKV projection + rope/V-transpose epilogue
    //    (768 blocks = 3/CU uniform, 2-phase dbuf pipeline)
    gemm_qkv_fused<<<dim3(48, 16), dim3(256), 0, stream>>>(
        hidden_bf, WqkvT, qk_bf, v_t);

    // 3. two-pass MFMA attention, uniform-duration 512x512 blocks
    attn_mfma<<<dim3(512), dim3(512), 0, stream>>>(
        qk_bf, v_t, bias_diag, soff, AO_bf);

    // 4. output projection (512 blocks = 2/CU, 2-phase dbuf pipeline)
    gemm_bf16_bt<<<dim3(2048 / 64, 2048 / 128), dim3(256), 0, stream>>>(
        AO_bf, WoT, out, 2048, 2048, 2048);
}

// Round 7
// 197.488 us; speedup vs baseline: 1.8846x; 1.0287x over previous
//
#include <hip/hip_runtime.h>
#include <cstdint>
#include <cstddef>

// Problem constants
#define BB   2
#define SS   1024
#define HID  2048
#define HH   32
#define KVHH 8
#define DD   64
#define NQKV 3072   // fused QKV projection width: 2048 q + 512 k + 512 v
#define QKW  2560   // qk_bf row width: 2048 q + 512 k

typedef __attribute__((ext_vector_type(8))) short bf16x8;
typedef __attribute__((ext_vector_type(4))) float f32x4;
typedef __attribute__((ext_vector_type(4))) unsigned int u32x4;

__device__ __forceinline__ unsigned short f2bf(float f) {
    unsigned int u = __float_as_uint(f);
    unsigned int r = (u + 0x7fffu + ((u >> 16) & 1u)) >> 16;
    return (unsigned short)r;
}

// raw v_exp_f32: D = 2^S0 (inputs are pre-scaled by log2e)
__device__ __forceinline__ float ex2(float x) {
    float r; asm("v_exp_f32 %0, %1" : "=v"(r) : "v"(x)); return r;
}

// async global->LDS 16B (wave-uniform LDS base + lane*16 layout required)
__device__ __forceinline__ void g2l16(const unsigned short* g, unsigned short* l) {
    __builtin_amdgcn_global_load_lds(
        (__attribute__((address_space(1))) void*)(unsigned short*)g,
        (__attribute__((address_space(3))) void*)l,
        16, 0, 0);
}

// ---------------------------------------------------------------------------
// prep (vectorized): z=0..3 weight transpose+convert (64x64 tiles, float4
// reads, ushort4 writes); z=4 hidden fp32->bf16 straight convert.
// ---------------------------------------------------------------------------
__global__ __launch_bounds__(256) void prep(
    const float* __restrict__ hidden,
    const float* __restrict__ Wq, const float* __restrict__ Wk,
    const float* __restrict__ Wv, const float* __restrict__ Wo,
    unsigned short* __restrict__ hidden_bf,
    unsigned short* __restrict__ WqkvT,
    unsigned short* __restrict__ WoT)
{
    const int z   = blockIdx.z;
    const int tid = threadIdx.x;

    if (z == 4) {   // hidden convert, 2048x2048, 64x64 tile
        int r0 = blockIdx.y * 64, c0 = blockIdx.x * 64;
        #pragma unroll
        for (int p = 0; p < 4; ++p) {
            int f = tid + p * 256;            // 0..1023
            int row = r0 + (f >> 4), c4 = c0 + (f & 15) * 4;
            float4 v = *(const float4*)&hidden[(size_t)row * 2048 + c4];
            ushort4 o;
            o.x = f2bf(v.x); o.y = f2bf(v.y); o.z = f2bf(v.z); o.w = f2bf(v.w);
            *(ushort4*)&hidden_bf[(size_t)row * 2048 + c4] = o;
        }
        return;
    }

    const float* W;
    unsigned short* Wt;
    int N;
    if (z == 0)      { W = Wq; Wt = WqkvT;                        N = 2048; }
    else if (z == 1) { W = Wk; Wt = WqkvT + (size_t)2048 * 2048;  N = 512;  }
    else if (z == 2) { W = Wv; Wt = WqkvT + (size_t)2560 * 2048;  N = 512;  }
    else             { W = Wo; Wt = WoT;                          N = 2048; }
    if (blockIdx.x * 64 >= N) return;

    // 64x64 transpose tile via LDS, stride 68 (2-way bank alias only)
    __shared__ float t[64][68];
    const int n0 = blockIdx.x * 64, k0 = blockIdx.y * 64;
    #pragma unroll
    for (int p = 0; p < 4; ++p) {
        int f = tid + p * 256;
        int row = f >> 4, c4 = (f & 15) * 4;     // row=k_local, c4=n_local
        float4 v = *(const float4*)&W[(size_t)(k0 + row) * N + n0 + c4];
        t[row][c4 + 0] = v.x; t[row][c4 + 1] = v.y;
        t[row][c4 + 2] = v.z; t[row][c4 + 3] = v.w;
    }
    __syncthreads();
    #pragma unroll
    for (int p = 0; p < 4; ++p) {
        int f = tid + p * 256;
        int nrow = f >> 4, kc4 = (f & 15) * 4;   // output row=n, col=k
        ushort4 o;
        o.x = f2bf(t[kc4 + 0][nrow]);
        o.y = f2bf(t[kc4 + 1][nrow]);
        o.z = f2bf(t[kc4 + 2][nrow]);
        o.w = f2bf(t[kc4 + 3][nrow]);
        *(ushort4*)&Wt[(size_t)(n0 + nrow) * 2048 + k0 + kc4] = o;
    }
}

// ---------------------------------------------------------------------------
// Fused QKV GEMM + rope/V-transpose epilogue. Tile 128(M) x 64(N), BK=64,
// 2-phase double-buffered swizzled global_load_lds staging.
// Grid (48, 16) = 768 blocks = 3/CU uniform (LDS 48KB -> 3 blocks fit).
// q rows scaled by 0.125*log2(e): attention uses raw v_exp_f32 (2^x).
// ---------------------------------------------------------------------------
__global__ __launch_bounds__(256) void gemm_qkv_fused(
    const unsigned short* __restrict__ A,     // hidden_bf [2048][2048]
    const unsigned short* __restrict__ Bt,    // WqkvT [3072][2048]
    unsigned short* __restrict__ qk_bf,       // [2048][2560]
    unsigned short* __restrict__ v_t)         // [1024][1024]
{
    __shared__ __align__(16) char smem[49152];   // 2 x (A 16KB + B 8KB)
    float* Ctf = (float*)smem;                   // [128][65] epilogue alias

    const int tid  = threadIdx.x;
    const int lane = tid & 63;
    const int wave = tid >> 6;
    const int quad = lane >> 4;
    const int l15  = lane & 15;
    const int wm = (wave >> 1) * 64, wn = (wave & 1) * 32;
    const int m0 = blockIdx.y * 128, n0 = blockIdx.x * 64;
    const int K = 2048;

    f32x4 acc[4][2] = {};

#define STAGE_Q(k0s, buf) do {                                                \
    unsigned short* Ad = (unsigned short*)(smem + (buf) * 24576);             \
    unsigned short* Bd = (unsigned short*)(smem + (buf) * 24576 + 16384);     \
    _Pragma("unroll")                                                         \
    for (int p = 0; p < 4; ++p) {                                             \
        int ci = tid + p * 256;                                               \
        int row_ = ci >> 3, sc_ = (ci & 7) ^ (row_ & 7);                      \
        g2l16(&A[(size_t)(m0 + row_) * K + (k0s) + sc_ * 8], Ad + ci * 8);    \
    }                                                                         \
    _Pragma("unroll")                                                         \
    for (int p = 0; p < 2; ++p) {                                             \
        int ci = tid + p * 256;                                               \
        int row_ = ci >> 3, sc_ = (ci & 7) ^ (row_ & 7);                      \
        g2l16(&Bt[(size_t)(n0 + row_) * K + (k0s) + sc_ * 8], Bd + ci * 8);   \
    } } while (0)

    STAGE_Q(0, 0);
    __syncthreads();
    int cur = 0;
    for (int k0 = 0; k0 < K; k0 += 64) {
        if (k0 + 64 < K) STAGE_Q(k0 + 64, cur ^ 1);
        const short* Ab = (const short*)(smem + cur * 24576);
        const short* Bb = (const short*)(smem + cur * 24576 + 16384);

        #pragma unroll
        for (int s = 0; s < 2; ++s) {
            bf16x8 af[4], bfr[2];
            #pragma unroll
            for (int i = 0; i < 4; ++i) {
                int row = wm + i * 16 + l15;
                af[i] = *(const bf16x8*)(Ab + row * 64 +
                        ((((s << 2) | quad) ^ (row & 7)) * 8));
            }
            #pragma unroll
            for (int j = 0; j < 2; ++j) {
                int row = wn + j * 16 + l15;
                bfr[j] = *(const bf16x8*)(Bb + row * 64 +
                        ((((s << 2) | quad) ^ (row & 7)) * 8));
            }
            #pragma unroll
            for (int i = 0; i < 4; ++i)
                #pragma unroll
                for (int j = 0; j < 2; ++j)
                    acc[i][j] = __builtin_amdgcn_mfma_f32_16x16x32_bf16(
                        af[i], bfr[j], acc[i][j], 0, 0, 0);
        }
        __syncthreads();
        cur ^= 1;
    }

    // ---- epilogue: fragments -> Ct[128][65] fp32 (aliases staging) ----
    #pragma unroll
    for (int i = 0; i < 4; ++i)
        #pragma unroll
        for (int j = 0; j < 2; ++j)
            #pragma unroll
            for (int rg = 0; rg < 4; ++rg)
                Ctf[(wm + i * 16 + quad * 4 + rg) * 65 + wn + j * 16 + l15]
                    = acc[i][j][rg];
    __syncthreads();

    const int bx = blockIdx.x;
    const int b  = m0 >> 10;           // batch (tile never straddles)
    const int s0 = m0 & 1023;

    if (bx < 40) {
        // rope q/k: qk_bf col base = bx*64 (q: 0..2047; k: 2048 + (bx-32)*64)
        const int hc = bx * 64;
        // q scaled by 0.125 * log2(e) so attention can use exp2 directly
        const float scale = (bx < 32) ? 0.18033688011112042f : 1.0f;
        #pragma unroll
        for (int p = 0; p < 4; ++p) {
            int idx = tid + p * 256;          // 128 rows x 8 t-groups
            int row = idx >> 3, t0 = (idx & 7) * 4;
            int s = s0 + row;
            ushort4 o1, o2;
            #pragma unroll
            for (int k = 0; k < 4; ++k) {
                int t = t0 + k;
                float x1 = Ctf[row * 65 + t];
                float x2 = Ctf[row * 65 + t + 32];
                float inv = __expf(-(float)t * 0.28782313662425572f);
                float ang = (float)s * inv;
                float c  = __cosf(ang);
                float sn = __sinf(ang);
                ((unsigned short*)&o1)[k] = f2bf((x1 * c - x2 * sn) * scale);
                ((unsigned short*)&o2)[k] = f2bf((x2 * c + x1 * sn) * scale);
            }
            unsigned short* dst = qk_bf + (size_t)(m0 + row) * QKW + hc;
            *(ushort4*)&dst[t0]      = o1;
            *(ushort4*)&dst[t0 + 32] = o2;
        }
    } else {
        // v transpose: v_t[(b*512 + (bx-40)*64 + c)][s0 + srow]
        const int vb = b * 512 + (bx - 40) * 64;
        #pragma unroll
        for (int p = 0; p < 8; ++p) {
            int idx = tid + p * 256;          // 64 c x 32 s-groups
            int c = idx >> 5, srow = (idx & 31) * 4;
            ushort4 o;
            #pragma unroll
            for (int k = 0; k < 4; ++k)
                ((unsigned short*)&o)[k] = f2bf(Ctf[(srow + k) * 65 + c]);
            *(ushort4*)&v_t[(size_t)(vb + c) * 1024 + s0 + srow] = o;
        }
    }
#undef STAGE_Q
}

// ---------------------------------------------------------------------------
// bf16 MFMA GEMM, B-transposed (Wo projection). Tile 128x64, BK=64,
// 2-phase double-buffered swizzled staging. 512 blocks = 2/CU uniform.
// ---------------------------------------------------------------------------
__global__ __launch_bounds__(256) void gemm_bf16_bt(
    const unsigned short* __restrict__ A,
    const unsigned short* __restrict__ Bt,
    float* __restrict__ C, int M, int N, int K)
{
    __shared__ __align__(16) char smem[49152];   // 2 x (A 16KB + B 8KB)

    const int tid  = threadIdx.x;
    const int lane = tid & 63;
    const int wave = tid >> 6;
    const int quad = lane >> 4;
    const int l15  = lane & 15;
    const int wm = (wave >> 1) * 64, wn = (wave & 1) * 32;
    const int m0 = blockIdx.y * 128, n0 = blockIdx.x * 64;

    f32x4 acc[4][2] = {};

#define STAGE_O(k0s, buf) do {                                                \
    unsigned short* Ad = (unsigned short*)(smem + (buf) * 24576);             \
    unsigned short* Bd = (unsigned short*)(smem + (buf) * 24576 + 16384);     \
    _Pragma("unroll")                                                         \
    for (int p = 0; p < 4; ++p) {                                             \
        int ci = tid + p * 256;                                               \
        int row_ = ci >> 3, sc_ = (ci & 7) ^ (row_ & 7);                      \
        g2l16(&A[(size_t)(m0 + row_) * K + (k0s) + sc_ * 8], Ad + ci * 8);    \
    }                                                                         \
    _Pragma("unroll")                                                         \
    for (int p = 0; p < 2; ++p) {                                             \
        int ci = tid + p * 256;                                               \
        int row_ = ci >> 3, sc_ = (ci & 7) ^ (row_ & 7);                      \
        g2l16(&Bt[(size_t)(n0 + row_) * K + (k0s) + sc_ * 8], Bd + ci * 8);   \
    } } while (0)

    STAGE_O(0, 0);
    __syncthreads();
    int cur = 0;
    for (int k0 = 0; k0 < K; k0 += 64) {
        if (k0 + 64 < K) STAGE_O(k0 + 64, cur ^ 1);
        const short* Ab = (const short*)(smem + cur * 24576);
        const short* Bb = (const short*)(smem + cur * 24576 + 16384);

        #pragma unroll
        for (int s = 0; s < 2; ++s) {
            bf16x8 af[4], bfr[2];
            #pragma unroll
            for (int i = 0; i < 4; ++i) {
                int row = wm + i * 16 + l15;
                af[i] = *(const bf16x8*)(Ab + row * 64 +
                        ((((s << 2) | quad) ^ (row & 7)) * 8));
            }
            #pragma unroll
            for (int j = 0; j < 2; ++j) {
                int row = wn + j * 16 + l15;
                bfr[j] = *(const bf16x8*)(Bb + row * 64 +
                        ((((s << 2) | quad) ^ (row & 7)) * 8));
            }
            #pragma unroll
            for (int i = 0; i < 4; ++i)
                #pragma unroll
                for (int j = 0; j < 2; ++j)
                    acc[i][j] = __builtin_amdgcn_mfma_f32_16x16x32_bf16(
                        af[i], bfr[j], acc[i][j], 0, 0, 0);
        }
        __syncthreads();
        cur ^= 1;
    }

    #pragma unroll
    for (int i = 0; i < 4; ++i) {
        int grow = m0 + wm + i * 16 + quad * 4;
        #pragma unroll
        for (int j = 0; j < 2; ++j) {
            int gcol = n0 + wn + j * 16 + l15;
            #pragma unroll
            for (int rg = 0; rg < 4; ++rg)
                C[(size_t)(grow + rg) * N + gcol] = acc[i][j][rg];
        }
    }
#undef STAGE_O
}

// ---------------------------------------------------------------------------
// MFMA flash attention, two-pass (r7): k-split wave groups, shared staging.
// 1024 blocks x 512 threads; block = one (qt,h,b) with balanced qtab
// placement (each CU's 4 resident blocks have qt summing to 30; heavy
// first). 8 waves = (w4 = q-subtile, grp = k-half of each 64-k tile): all
// waves consume the SAME staged K/V tile -> LDS 36.5KB -> 4 blocks/CU
// (32 waves). Per-wave state halved vs r6 (acc[2], pk[2][2]) -> VGPR<=64.
// Cross-group combine (l via red, oacc via Fred) as r5/r6. exp uses raw
// v_exp_f32 (2^x): q pre-scaled by 0.125*log2e, bias scaled at LDS fill.
// ---------------------------------------------------------------------------
__global__ __launch_bounds__(512, 8) void attn_mfma(
    const unsigned short* __restrict__ qk_bf,   // [2048][2560]
    const unsigned short* __restrict__ v_t,     // [1024][1024]
    const float* __restrict__ bias_diag,
    const float* __restrict__ soff,
    unsigned short* __restrict__ AO)            // [2048][2048] bf16
{
    static const unsigned char qtab[16] =
        {15, 14, 13, 12, 10, 11, 8, 9, 4, 5, 6, 7, 1, 0, 3, 2};
    const int id = (int)blockIdx.x;             // 1024 blocks
    const int vq = id >> 8;                     // launch round 0..3
    const int c  = id & 255;                    // ~CU index
    const int qt = qtab[(vq << 2) | (c & 3)];
    const int bh = c >> 2;                      // 0..63
    const int h  = bh & 31;
    const int b  = bh >> 5;
    const int kh = h >> 2;
    const int tid  = threadIdx.x;
    const int lane = tid & 63;
    const int wave = tid >> 6;                  // 0..7
    const int grp  = wave >> 2;                 // k-half of each 64-k tile
    const int w4   = wave & 3;                  // q sub-tile
    const int quad = lane >> 4;
    const int l15  = lane & 15;
    const int q0   = qt * 64;

    __shared__ short Ks[2][4096];   // dbuf [64 k][64 d] bf16, chunk-swizzled
    __shared__ short Vs[2][4096];   // dbuf [64 d][64 k] bf16, chunk-swizzled
    __shared__ float bd_s[1024];    // bias * log2e
    __shared__ float red[2][64];    // lp cross-group exchange
    float* Fred = (float*)&Ks[0][0];   // 64x64 f32 = 16KB, alias (post-loop)

    for (int i = tid; i < 1024; i += 512)
        bd_s[i] = bias_diag[h * 1024 + i] * 1.4426950408889634f;

    const unsigned short* Kg = qk_bf + (size_t)(b * SS) * QKW + 2048 + kh * 64;
    const unsigned short* Vg = v_t + (size_t)(b * 512 + kh * 64) * SS;

    const int qrow = q0 + w4 * 16 + l15;        // this lane's q (S^T column)

    const unsigned short* Qg =
        qk_bf + (size_t)(b * SS + q0 + w4 * 16) * QKW + h * 64;
    bf16x8 qf0 = *(const bf16x8*)(Qg + (size_t)l15 * QKW + quad * 8);
    bf16x8 qf1 = *(const bf16x8*)(Qg + (size_t)l15 * QKW + 32 + quad * 8);

// stage one 64x64 bf16 tile (512 x 16B chunks, 1/thread), source-side XOR
// swizzle: LDS chunk (row, c') holds global chunk (row, c'^(row&7))
#define STAGE_K(j, buf) do {                                                  \
    int ci = tid;                                                             \
    int row_ = ci >> 3, sc_ = (ci & 7) ^ (row_ & 7);                          \
    g2l16(Kg + (size_t)((j) * 64 + row_) * QKW + sc_ * 8,                     \
          (unsigned short*)&Ks[buf][ci * 8]);                                 \
} while (0)

#define STAGE_V(j, buf) do {                                                  \
    int ci = tid;                                                             \
    int row_ = ci >> 3, sc_ = (ci & 7) ^ (row_ & 7);                          \
    g2l16(Vg + (size_t)row_ * SS + (j) * 64 + sc_ * 8,                        \
          (unsigned short*)&Vs[buf][ci * 8]);                                 \
} while (0)

    // ---------------- pass 1: l ----------------
    float lpa[4] = {0.f, 0.f, 0.f, 0.f};
    STAGE_K(0, 0);
    __syncthreads();                            // also covers bd_s
    int cur = 0;
    for (int j = 0; j <= qt; ++j) {
        if (j < qt) STAGE_K(j + 1, cur ^ 1);
        const short* Kb = Ks[cur];
        const bool diag = (j == qt);

        f32x4 acc[2] = {};
        #pragma unroll
        for (int nn = 0; nn < 2; ++nn) {
            int nb = 2 * grp + nn;
            if (diag && nb > w4) continue;
            int row = nb * 16 + l15, sw = row & 7;
            bf16x8 a0 = *(const bf16x8*)(Kb + row * 64 + ((quad ^ sw) * 8));
            bf16x8 a1 = *(const bf16x8*)(Kb + row * 64 + (((quad + 4) ^ sw) * 8));
            acc[nn] = __builtin_amdgcn_mfma_f32_16x16x32_bf16(a0, qf0, acc[nn], 0, 0, 0);
            acc[nn] = __builtin_amdgcn_mfma_f32_16x16x32_bf16(a1, qf1, acc[nn], 0, 0, 0);
        }
        if (!diag) {
            #pragma unroll
            for (int nn = 0; nn < 2; ++nn) {
                int rel0 = qrow - (j * 64 + (2 * grp + nn) * 16 + quad * 4);
                #pragma unroll
                for (int r = 0; r < 4; ++r)
                    lpa[r] += ex2(acc[nn][r] + bd_s[rel0 - r]);
            }
        } else {
            #pragma unroll
            for (int nn = 0; nn < 2; ++nn) {
                int nb = 2 * grp + nn;
                if (nb > w4) continue;
                #pragma unroll
                for (int r = 0; r < 4; ++r) {
                    int rel = qrow - (j * 64 + nb * 16 + quad * 4 + r);
                    if (rel >= 0) lpa[r] += ex2(acc[nn][r] + bd_s[rel]);
                }
            }
        }
        __syncthreads();
        cur ^= 1;
    }

    // lp: quad-reduce within wave, then cross-group (k-half) via LDS
    float lp = (lpa[0] + lpa[1]) + (lpa[2] + lpa[3]);
    lp += __shfl_xor(lp, 16, 64);
    lp += __shfl_xor(lp, 32, 64);
    if (quad == 0) red[grp][w4 * 16 + l15] = lp;
    __syncthreads();
    lp = red[0][w4 * 16 + l15] + red[1][w4 * 16 + l15];
    const float invl = 1.f / lp;
    const float cl   = fabsf(soff[h] + 1.f) / (float)(qrow + 1) * lp;

    // ---------------- pass 2: output ----------------
    f32x4 oacc[4] = {};
    STAGE_K(0, 0);
    STAGE_V(0, 0);
    __syncthreads();
    cur = 0;
    for (int j = 0; j <= qt; ++j) {
        if (j < qt) { STAGE_K(j + 1, cur ^ 1); STAGE_V(j + 1, cur ^ 1); }
        const short* Kb = Ks[cur];
        const short* Vb = Vs[cur];
        const bool diag = (j == qt);

        f32x4 acc[2] = {};
        #pragma unroll
        for (int nn = 0; nn < 2; ++nn) {
            int nb = 2 * grp + nn;
            if (diag && nb > w4) continue;
            int row = nb * 16 + l15, sw = row & 7;
            bf16x8 a0 = *(const bf16x8*)(Kb + row * 64 + ((quad ^ sw) * 8));
            bf16x8 a1 = *(const bf16x8*)(Kb + row * 64 + (((quad + 4) ^ sw) * 8));
            acc[nn] = __builtin_amdgcn_mfma_f32_16x16x32_bf16(a0, qf0, acc[nn], 0, 0, 0);
            acc[nn] = __builtin_amdgcn_mfma_f32_16x16x32_bf16(a1, qf1, acc[nn], 0, 0, 0);
        }

        // w = relu(exp2(s' + bias') - cl); full tiles are mask-free
        unsigned int pk[2][2];
        if (!diag) {
            #pragma unroll
            for (int nn = 0; nn < 2; ++nn) {
                float w[4];
                int rel0 = qrow - (j * 64 + (2 * grp + nn) * 16 + quad * 4);
                #pragma unroll
                for (int r = 0; r < 4; ++r)
                    w[r] = fmaxf(ex2(acc[nn][r] + bd_s[rel0 - r]) - cl, 0.f);
                asm("v_cvt_pk_bf16_f32 %0, %1, %2" : "=v"(pk[nn][0]) : "v"(w[0]), "v"(w[1]));
                asm("v_cvt_pk_bf16_f32 %0, %1, %2" : "=v"(pk[nn][1]) : "v"(w[2]), "v"(w[3]));
            }
        } else {
            #pragma unroll
            for (int nn = 0; nn < 2; ++nn) {
                int nb = 2 * grp + nn;
                float w[4];
                #pragma unroll
                for (int r = 0; r < 4; ++r) {
                    int rel = qrow - (j * 64 + nb * 16 + quad * 4 + r);
                    float e = 0.f;
                    if (rel >= 0)
                        e = fmaxf(ex2(acc[nn][r] + bd_s[rel]) - cl, 0.f);
                    w[r] = e;
                }
                asm("v_cvt_pk_bf16_f32 %0, %1, %2" : "=v"(pk[nn][0]) : "v"(w[0]), "v"(w[1]));
                asm("v_cvt_pk_bf16_f32 %0, %1, %2" : "=v"(pk[nn][1]) : "v"(w[2]), "v"(w[3]));
            }
        }
        unsigned int ppk[2][2];
        #pragma unroll
        for (int nn = 0; nn < 2; ++nn) {
            ppk[nn][0] = __shfl_xor(pk[nn][0], 16, 64);
            ppk[nn][1] = __shfl_xor(pk[nn][1], 16, 64);
        }

        // PV for this group's 32-k half (the s=grp block of the r6 s-loop):
        // slot (quad,e) <-> kpos permutation matched by V chunk cv + 4*grp.
        if (!(diag && grp == 1 && w4 < 2)) {     // dead kpos block on diag
            const bool oddq = quad & 1;
            const int  cv   = ((quad & 1) << 1) | (quad >> 1);   // 0,2,1,3
            unsigned int w0 = oddq ? ppk[1][0] : pk[0][0];
            unsigned int w1 = oddq ? ppk[1][1] : pk[0][1];
            unsigned int w2 = oddq ? pk[1][0]  : ppk[0][0];
            unsigned int w3 = oddq ? pk[1][1]  : ppk[0][1];
            u32x4 t; t[0] = w0; t[1] = w1; t[2] = w2; t[3] = w3;
            bf16x8 pf = __builtin_bit_cast(bf16x8, t);
            #pragma unroll
            for (int nd = 0; nd < 4; ++nd) {
                int rowv = nd * 16 + l15, swv = rowv & 7;
                bf16x8 vf = *(const bf16x8*)(Vb + rowv * 64 + (((cv + 4 * grp) ^ swv) * 8));
                oacc[nd] = __builtin_amdgcn_mfma_f32_16x16x32_bf16(pf, vf, oacc[nd], 0, 0, 0);
            }
        }
        __syncthreads();
        cur ^= 1;
    }

    // ---- cross-group oacc reduce (grp1 -> Fred, grp0 adds) + output ----
    if (grp == 1) {
        #pragma unroll
        for (int nd = 0; nd < 4; ++nd)
            #pragma unroll
            for (int r = 0; r < 4; ++r)
                Fred[(w4 * 16 + quad * 4 + r) * 64 + nd * 16 + l15] = oacc[nd][r];
    }
    __syncthreads();
    if (grp == 0) {
        float invl_r[4];
        #pragma unroll
        for (int r = 0; r < 4; ++r)
            invl_r[r] = __shfl(invl, quad * 4 + r, 64);
        unsigned short* aop =
            AO + (size_t)(b * SS + q0 + w4 * 16 + quad * 4) * 2048 + h * 64 + l15;
        #pragma unroll
        for (int nd = 0; nd < 4; ++nd)
            #pragma unroll
            for (int r = 0; r < 4; ++r) {
                float o = (oacc[nd][r] +
                           Fred[(w4 * 16 + quad * 4 + r) * 64 + nd * 16 + l15])
                          * invl_r[r];
                aop[(size_t)r * 2048 + nd * 16] = f2bf(o);
            }
    }
#undef STAGE_K
#undef STAGE_V
}

// ---------------------------------------------------------------------------
extern "C" void kernel_launch(void* const* d_in, const int* in_sizes, int n_in,
                              void* d_out, int out_size, void* d_ws, size_t ws_size,
                              hipStream_t stream)
{
    const float* hidden    = (const float*)d_in[0];
    const float* Wq        = (const float*)d_in[2];
    const float* Wk        = (const float*)d_in[3];
    const float* Wv        = (const float*)d_in[4];
    const float* Wo        = (const float*)d_in[5];
    const float* bias_diag = (const float*)d_in[6];
    const float* soff      = (const float*)d_in[7];
    float* out = (float*)d_out;

    // Workspace aliasing:
    //  A [0,20.97M): hidden_bf(8.39) + WqkvT(12.58) -- inputs of QKV gemm.
    //                AO_bf at [12.58M..) only AFTER WqkvT is dead (attention
    //                writes AO_bf after the QKV gemm consumed WqkvT).
    //  B [20.97M,29.36M): WoT
    //  C [29.36M,41.94M): qk_bf(10.49M) + v_t(2.10M)
    char* wsb = (char*)d_ws;
    unsigned short* hidden_bf = (unsigned short*)wsb;
    unsigned short* WqkvT     = (unsigned short*)(wsb + (size_t)8388608);
    unsigned short* AO_bf     = (unsigned short*)(wsb + (size_t)12582912);
    unsigned short* WoT       = (unsigned short*)(wsb + (size_t)20971520);
    unsigned short* qk_bf     = (unsigned short*)(wsb + (size_t)29360128);
    unsigned short* v_t       = (unsigned short*)(wsb + (size_t)29360128 + (size_t)2048 * 2560 * 2);

    // 1. weight transposes + hidden convert (one launch, vectorized)
    prep<<<dim3(32, 32, 5), dim3(256), 0, stream>>>(
        hidden, Wq, Wk, Wv, Wo, hidden_bf, WqkvT, WoT);

    // 2. fused QKV projection + rope/V-transpose epilogue
    //    (768 blocks = 3/CU uniform, 2-phase dbuf pipeline)
    gemm_qkv_fused<<<dim3(48, 16), dim3(256), 0, stream>>>(
        hidden_bf, WqkvT, qk_bf, v_t);

    // 3. two-pass MFMA attention, k-split groups, 1024 blocks = 4/CU
    attn_mfma<<<dim3(1024), dim3(512), 0, stream>>>(
        qk_bf, v_t, bias_diag, soff, AO_bf);

    // 4. output projection (512 blocks = 2/CU, 2-phase dbuf pipeline)
    gemm_bf16_bt<<<dim3(2048 / 64, 2048 / 128), dim3(256), 0, stream>>>(
        AO_bf, WoT, out, 2048, 2048, 2048);
}